// Round 14
// baseline (552.733 us; speedup 1.0000x reference)
//
#include <hip/hip_runtime.h>
#include <hip/hip_bf16.h>

// Problem constants
#define NBS   128
#define NF    182      // 20 text + 150 ocr/obj + 12 decode
#define NP    192      // padded N for MFMA tiling
#define DMODEL 768
#define NH    12
#define HDIM  64
#define SEQT  20
#define ROCR  150

typedef __attribute__((ext_vector_type(4))) float  f32x4;
typedef __attribute__((ext_vector_type(8))) short  s16x8;
typedef __attribute__((ext_vector_type(4))) unsigned int u32x4;
using bf16 = __hip_bfloat16;

#define SB()    __builtin_amdgcn_sched_barrier(0)
#define BAR()   __builtin_amdgcn_s_barrier()

// global->LDS direct copy, 16B per lane. LDS dest linear in lane (base+lane*16).
__device__ __forceinline__ void gload_lds16(const void* g, void* l) {
    auto gp = (const __attribute__((address_space(1))) unsigned int*)((unsigned long long)g);
    auto lp = (__attribute__((address_space(3))) unsigned int*)(unsigned int)((unsigned long long)l);
    __builtin_amdgcn_global_load_lds(gp, lp, 16, 0, 0);
}

// ---------------------------------------------------------------------------
// Kernel 0: PREP (convert + pack_adj merged; saves one launch).
// Blocks [0, 9600): fp32->bf16: hs -> hsb; Wq|Wk|Wv -> Wb2 per-head layout
//   (Wb2 row R = h*192 + which*64 + r0 holds W_which[h*64+r0][:]).
// Blocks [9600, 28800): pack spatial adjacency -> bitmask (b,12,150,3).
// ---------------------------------------------------------------------------
#define CVT_BLOCKS 9600
__global__ __launch_bounds__(256) void prep(
    const float* __restrict__ hs,
    const float* __restrict__ Wq, const float* __restrict__ Wk, const float* __restrict__ Wv,
    const float* __restrict__ adj,
    bf16* __restrict__ hsb, bf16* __restrict__ Wb2,
    unsigned long long* __restrict__ bits)
{
    __shared__ float tile[ROCR * NH];       // used by pack branch only
    if (blockIdx.x < CVT_BLOCKS) {
        const size_t HT = (size_t)NBS * NF * DMODEL / 8;        // 2,236,416
        const size_t WT = 3ull * DMODEL * DMODEL / 8;           // 221,184
        size_t i = (size_t)blockIdx.x * 256 + threadIdx.x;
        if (i >= HT + WT) return;
        const float* src; bf16* dst;
        if (i < HT) {
            size_t e = i * 8; src = hs + e; dst = hsb + e;
        } else {
            size_t e = (i - HT) * 8;
            int R = (int)(e / DMODEL), c = (int)(e % DMODEL);
            int h = R / 192, t2 = (R % 192) / 64, r0 = R % 64;
            src = (t2 == 0 ? Wq : t2 == 1 ? Wk : Wv) + (size_t)(h * 64 + r0) * DMODEL + c;
            dst = Wb2 + e;
        }
        float4 a = *reinterpret_cast<const float4*>(src);
        float4 b = *reinterpret_cast<const float4*>(src + 4);
        union { s16x8 v; bf16 h8[8]; } u;
        u.h8[0] = __float2bfloat16(a.x); u.h8[1] = __float2bfloat16(a.y);
        u.h8[2] = __float2bfloat16(a.z); u.h8[3] = __float2bfloat16(a.w);
        u.h8[4] = __float2bfloat16(b.x); u.h8[5] = __float2bfloat16(b.y);
        u.h8[6] = __float2bfloat16(b.z); u.h8[7] = __float2bfloat16(b.w);
        *reinterpret_cast<s16x8*>(dst) = u.v;
    } else {
        const int pb = blockIdx.x - CVT_BLOCKS;
        const int b = pb / ROCR, r = pb - b * ROCR;
        const int tid = threadIdx.x, lane = tid & 63, w = tid >> 6;
        const float* src = adj + ((size_t)b * ROCR + r) * (ROCR * NH);
        for (int i = tid; i < ROCR * NH; i += 256) tile[i] = src[i];
        __syncthreads();
        for (int c = w; c < NH * 3; c += 4) {
            int hh = c / 3, wd = c - hh * 3;
            int k = wd * 64 + lane;
            int j = k - SEQT;
            bool v = false;
            if (j >= 0 && j < ROCR) v = (tile[j * NH + hh] > 0.5f);
            unsigned long long m = __ballot(v);
            if (lane == 0) bits[(((size_t)b * NH + hh) * ROCR + r) * 3 + wd] = m;
        }
    }
}

// ---------------------------------------------------------------------------
// Kernel 2: FUSED per-(b,h) QKV-projection + attention.
// R13 body (verified 156us) with ONE change: Q transits through GLOBAL qg
// (single-pass epilogue preserved -> no acc spill, unlike R12), freeing the
// 24KB Q LDS region: LDS 78.8 -> 53.4KB -> 3 blocks/CU (occupancy lever;
// R12 measured 32.7% at this footprint). Global-staging visibility pattern
// proven correct by R11. Attention = R12/R13-verified in-register-P body.
// LDS map:
//   [0..24576)      staging buf0 -> K[192][64] swz after GEMM
//   [24576..49152)  staging buf1 -> Vt[64][192] swz after GEMM
//   [49152..53376)  Lw bitmasks (176 x 3 u64);  [53376..53400) aw
// ---------------------------------------------------------------------------
#define KO2   0
#define VTO2  24576
#define LWO2  49152
#define AWO2  53376

__global__ __launch_bounds__(256, 3) void fused_qkv_attn(
    const bf16* __restrict__ hsb, const bf16* __restrict__ Wb2,
    const float* __restrict__ bq, const float* __restrict__ bk, const float* __restrict__ bv,
    const float* __restrict__ amask,
    const unsigned long long* __restrict__ bits,
    bf16* __restrict__ qg,
    float* __restrict__ out)
{
    __shared__ char L[53400];
    const int tid  = threadIdx.x;
    const int lane = tid & 63;
    const int wid  = tid >> 6;
    const int wr = wid >> 1, wc = wid & 1;      // 2x2 wave grid, 96x96 each
    const int lm = lane & 15, lg = lane >> 4;

    // m204 XCD chunking (1536 = 8*192): 12 head-blocks of one b on one XCD.
    const int flat = blockIdx.x;
    const int wgid = (flat & 7) * 192 + (flat >> 3);
    const int b = wgid / NH, h = wgid - b * NH;

    float* obase = out + (size_t)b * NF * DMODEL + h * HDIM;
    bf16*  qgb   = qg + (size_t)wgid * (176 * 64);

    // ---- masks + decode-row zeroing (independent of GEMM) ----
    if (wid == 0) {
        #pragma unroll
        for (int w = 0; w < 3; ++w) {
            int k = w * 64 + lane;
            bool v = (k < NF) && (amask[b * NF + k] == 0.0f);
            unsigned long long m = __ballot(v);
            if (lane == 0) ((unsigned long long*)(L + AWO2))[w] = m;
        }
    }
    for (int i = tid; i < 12 * 64; i += 256)
        obase[(size_t)(170 + (i >> 6)) * DMODEL + (i & 63)] = 0.f;
    __syncthreads();
    if (tid < 176) {
        int r = tid;
        unsigned long long s0 = 0, s1 = 0, s2 = 0;
        const unsigned long long DEC = 0xFFFull << 42;      // keys 170..181
        if (r < SEQT) {
            s2 = DEC;
        } else if (r < SEQT + ROCR) {
            const unsigned long long* bp = bits + (((size_t)b * NH + h) * ROCR + (r - SEQT)) * 3;
            s0 = bp[0]; s1 = bp[1]; s2 = bp[2] | DEC;
        }
        unsigned long long* aw = (unsigned long long*)(L + AWO2);
        unsigned long long* Lw = (unsigned long long*)(L + LWO2);
        Lw[r * 3 + 0] = s0 & aw[0];
        Lw[r * 3 + 1] = s1 & aw[1];
        Lw[r * 3 + 2] = s2 & aw[2];
    }

    // ---- Phase G: GEMM (verified BK=32 dbuf, counted vmcnt(6)) ----
    const char* gA = (const char*)(hsb + (size_t)b * NF * DMODEL);   // 192 rows (pad rows harmless)
    const char* gW = (const char*)(Wb2 + (size_t)h * 192 * DMODEL);

    f32x4 acc[6][6];
    #pragma unroll
    for (int i = 0; i < 6; ++i)
        #pragma unroll
        for (int j = 0; j < 6; ++j) acc[i][j] = (f32x4){0.f, 0.f, 0.f, 0.f};

    const int srow4 = tid >> 2, sch4 = tid & 3;

    auto ST = [&](int kt, int bsel) {
        char* dA = L + bsel * 24576;
        char* dW = dA + 12288;
        #pragma unroll
        for (int it = 0; it < 3; ++it) {
            int row = it * 64 + srow4;
            int lc = sch4 ^ ((row >> 1) & 3);
            size_t go = (size_t)row * 1536 + (size_t)kt * 64 + lc * 16;
            int o = row * 64 + sch4 * 16;
            gload_lds16(gA + go, dA + o);
            gload_lds16(gW + go, dW + o);
        }
    };
    auto CP = [&](int bsel) {
        const char* Ab = L + bsel * 24576;
        const char* Wp = Ab + 12288;
        s16x8 af[6], bf6[6];
        #pragma unroll
        for (int mi = 0; mi < 6; ++mi) {
            int r = 96 * wr + 16 * mi + lm;
            af[mi] = *reinterpret_cast<const s16x8*>(Ab + r * 64 + ((lg ^ ((r >> 1) & 3)) << 4));
        }
        #pragma unroll
        for (int ni = 0; ni < 6; ++ni) {
            int r = 96 * wc + 16 * ni + lm;
            bf6[ni] = *reinterpret_cast<const s16x8*>(Wp + r * 64 + ((lg ^ ((r >> 1) & 3)) << 4));
        }
        __builtin_amdgcn_s_setprio(1);
        #pragma unroll
        for (int mi = 0; mi < 6; ++mi)
            #pragma unroll
            for (int ni = 0; ni < 6; ++ni)
                acc[mi][ni] = __builtin_amdgcn_mfma_f32_16x16x32_bf16(af[mi], bf6[ni], acc[mi][ni], 0, 0, 0);
        __builtin_amdgcn_s_setprio(0);
    };

    ST(0, 0);
    ST(1, 1);
    for (int t = 0; t < 24; ++t) {
        if (t < 23) { asm volatile("s_waitcnt vmcnt(6)" ::: "memory"); }
        else        { asm volatile("s_waitcnt vmcnt(0)" ::: "memory"); }
        SB(); BAR(); SB();
        CP(t & 1);
        SB(); BAR();
        if (t + 2 < 24) ST(t + 2, t & 1);
    }
    BAR();   // all CP reads done before epilogue overwrites staging region

    // ---- epilogue (SINGLE PASS): acc+bias -> Q global / K LDS / Vt LDS ----
    float bias6[6];
    #pragma unroll
    for (int ni = 0; ni < 6; ++ni) {
        int c = 96 * wc + 16 * ni + lm;
        int whichc = c >> 6, cc = c & 63;
        const float* bp = (whichc == 0) ? bq : (whichc == 1) ? bk : bv;
        bias6[ni] = bp[h * 64 + cc];
    }
    #pragma unroll
    for (int mi = 0; mi < 6; ++mi) {
        #pragma unroll
        for (int ni = 0; ni < 6; ++ni) {
            int c = 96 * wc + 16 * ni + lm;
            #pragma unroll
            for (int j = 0; j < 4; ++j) {
                int row = 96 * wr + 16 * mi + 4 * lg + j;
                bf16 hv = __float2bfloat16(acc[mi][ni][j] + bias6[ni]);
                unsigned short us = *reinterpret_cast<unsigned short*>(&hv);
                if (c < 64) {
                    if (row < 176) qgb[row * 64 + c] = hv;
                } else if (c < 128) {
                    int cc = c - 64;
                    *reinterpret_cast<unsigned short*>(L + KO2 + row * 128 + ((2 * cc) ^ ((row & 7) << 4))) = us;
                } else if (row < NF) {
                    int d = c - 128;
                    *reinterpret_cast<unsigned short*>(L + VTO2 + d * 384 + ((2 * row) ^ ((d & 7) << 4))) = us;
                }
            }
        }
    }
    // zero Vt pad keys 182..191 (NaN containment)
    for (int i = tid; i < 64 * 10; i += 256) {
        int d = i / 10, k2 = NF + (i - d * 10);
        *reinterpret_cast<unsigned short*>(L + VTO2 + d * 384 + ((2 * k2) ^ ((d & 7) << 4))) = 0;
    }
    __syncthreads();    // drains vmcnt+lgkm: Q global writes + K/Vt LDS visible

    // ---- Q-preload from global (L2-hot, block-private region) ----
    s16x8 qf[3][2];
    #pragma unroll
    for (int bi = 0; bi < 3; ++bi) {
        int band = wid + 4 * bi;
        int qrow = ((band < 11) ? band * 16 : 0) + lm;      // safe dummy for band>=11
        const bf16* qb = qgb + qrow * 64;
        qf[bi][0] = *reinterpret_cast<const s16x8*>(qb + lg * 8);
        qf[bi][1] = *reinterpret_cast<const s16x8*>(qb + 32 + lg * 8);
    }

    // ---- Phase A: attention, P fully in-register (R12/R13-verified body) ----
    const unsigned long long* LwA = (const unsigned long long*)(L + LWO2);

    #pragma unroll
    for (int bi = 0; bi < 3; ++bi) {
        const int band = wid + 4 * bi;
        if (band >= 11) continue;
        const int q0 = band * 16;

        // masks for this lane's q-row (qrow = q0 + lm)
        const unsigned long long* lwp = LwA + (q0 + lm) * 3;
        unsigned long long mw0 = lwp[0], mw1 = lwp[1], mw2 = lwp[2];

        // swapped QK^T: sacc[t][j] = S[key=16t+4lg+j][qrow=q0+lm]
        f32x4 sacc[12];
        #pragma unroll
        for (int t = 0; t < 12; ++t) sacc[t] = (f32x4){0.f, 0.f, 0.f, 0.f};
        #pragma unroll
        for (int t = 0; t < 12; ++t) {
            int key = t * 16 + lm;
            const char* kb = L + KO2 + key * 128;
            int sw = (key & 7) << 4;
            s16x8 kf0 = *reinterpret_cast<const s16x8*>(kb + ((lg * 16) ^ sw));
            s16x8 kf1 = *reinterpret_cast<const s16x8*>(kb + ((64 + lg * 16) ^ sw));
            sacc[t] = __builtin_amdgcn_mfma_f32_16x16x32_bf16(kf0, qf[bi][0], sacc[t], 0, 0, 0);
            sacc[t] = __builtin_amdgcn_mfma_f32_16x16x32_bf16(kf1, qf[bi][1], sacc[t], 0, 0, 0);
        }

        // mask + per-lane softmax (this lane owns one q-row)
        float mx = -3.0e38f;
        #pragma unroll
        for (int t = 0; t < 12; ++t) {
            unsigned long long w = (t < 4) ? mw0 : (t < 8) ? mw1 : mw2;
            #pragma unroll
            for (int j = 0; j < 4; ++j) {
                int sh = ((t & 3) << 4) + 4 * lg + j;
                float s = sacc[t][j] * 0.125f;
                s = ((w >> sh) & 1ull) ? s : -3.0e38f;
                sacc[t][j] = s;
                mx = fmaxf(mx, s);
            }
        }
        mx = fmaxf(mx, __shfl_xor(mx, 16));
        mx = fmaxf(mx, __shfl_xor(mx, 32));
        float sum = 0.f;
        #pragma unroll
        for (int t = 0; t < 12; ++t)
            #pragma unroll
            for (int j = 0; j < 4; ++j) {
                float e = (sacc[t][j] > -1.0e37f) ? __expf(sacc[t][j] - mx) : 0.f;
                sacc[t][j] = e;
                sum += e;
            }
        sum += __shfl_xor(sum, 16);
        sum += __shfl_xor(sum, 32);
        float scl = (mx > -1.0e37f) ? 1.0f / sum : 0.f;

        // pack P rows to bf16 dword pairs per tile
        unsigned int p0[12], p1[12];
        #pragma unroll
        for (int t = 0; t < 12; ++t) {
            bf16 b0 = __float2bfloat16(sacc[t][0] * scl);
            bf16 b1 = __float2bfloat16(sacc[t][1] * scl);
            bf16 b2 = __float2bfloat16(sacc[t][2] * scl);
            bf16 b3 = __float2bfloat16(sacc[t][3] * scl);
            p0[t] = (unsigned int)*reinterpret_cast<unsigned short*>(&b0)
                  | ((unsigned int)*reinterpret_cast<unsigned short*>(&b1) << 16);
            p1[t] = (unsigned int)*reinterpret_cast<unsigned short*>(&b2)
                  | ((unsigned int)*reinterpret_cast<unsigned short*>(&b3) << 16);
        }

        // PV: build A-frags by lane exchange; dest (lg,ks) = keys 32ks+8lg+0..7
        f32x4 oacc[4];
        #pragma unroll
        for (int t = 0; t < 4; ++t) oacc[t] = (f32x4){0.f, 0.f, 0.f, 0.f};
        const bool hi = (lg & 1);
        #pragma unroll
        for (int ks = 0; ks < 6; ++ks) {
            unsigned int A0 = p0[2 * ks],     A1 = p1[2 * ks];
            unsigned int B0 = p0[2 * ks + 1], B1 = p1[2 * ks + 1];
            unsigned int u0 = __shfl_xor(A0, 16), u1 = __shfl_xor(A1, 16);
            unsigned int v0 = __shfl_xor(B0, 16), v1 = __shfl_xor(B1, 16);
            unsigned int hA0 = hi ? u0 : A0, hA1 = hi ? u1 : A1;
            unsigned int hA2 = hi ? A0 : u0, hA3 = hi ? A1 : u1;
            unsigned int hB0 = hi ? v0 : B0, hB1 = hi ? v1 : B1;
            unsigned int hB2 = hi ? B0 : v0, hB3 = hi ? B1 : v1;
            unsigned int xA0 = __shfl_xor(hA0, 32), xA1 = __shfl_xor(hA1, 32);
            unsigned int xA2 = __shfl_xor(hA2, 32), xA3 = __shfl_xor(hA3, 32);
            unsigned int xB0 = __shfl_xor(hB0, 32), xB1 = __shfl_xor(hB1, 32);
            unsigned int xB2 = __shfl_xor(hB2, 32), xB3 = __shfl_xor(hB3, 32);
            u32x4 f;
            if (lg == 0)      f = (u32x4){hA0, hA1, hA2, hA3};
            else if (lg == 1) f = (u32x4){xA0, xA1, xA2, xA3};
            else if (lg == 2) f = (u32x4){xB0, xB1, xB2, xB3};
            else              f = (u32x4){hB0, hB1, hB2, hB3};
            s16x8 pa;
            __builtin_memcpy(&pa, &f, 16);
            #pragma unroll
            for (int t2 = 0; t2 < 4; ++t2) {
                int d = t2 * 16 + lm;
                s16x8 vf = *reinterpret_cast<const s16x8*>(L + VTO2 + d * 384 + ((ks * 64 + lg * 16) ^ ((d & 7) << 4)));
                oacc[t2] = __builtin_amdgcn_mfma_f32_16x16x32_bf16(pa, vf, oacc[t2], 0, 0, 0);
            }
        }
        #pragma unroll
        for (int j = 0; j < 4; ++j) {
            int row = q0 + lg * 4 + j;
            if (row < 170) {
                #pragma unroll
                for (int t2 = 0; t2 < 4; ++t2)
                    obase[(size_t)row * DMODEL + t2 * 16 + lm] = oacc[t2][j];
            }
        }
    }
}

// ---------------------------------------------------------------------------
extern "C" void kernel_launch(void* const* d_in, const int* in_sizes, int n_in,
                              void* d_out, int out_size, void* d_ws, size_t ws_size,
                              hipStream_t stream)
{
    const float* hs    = (const float*)d_in[0];
    const float* amask = (const float*)d_in[1];
    const float* adj   = (const float*)d_in[2];
    const float* Wq    = (const float*)d_in[3];
    const float* bq    = (const float*)d_in[4];
    const float* Wk    = (const float*)d_in[5];
    const float* bk    = (const float*)d_in[6];
    const float* Wv    = (const float*)d_in[7];
    const float* bv    = (const float*)d_in[8];
    float* out = (float*)d_out;

    // workspace: Wb2 (3.54MB) | bits (5.53MB) | hsb (35.8MB) | qg (34.6MB)
    // (qg after hsb also provides the pad-row read slack for b=127)
    char* ws = (char*)d_ws;
    bf16* Wb2 = (bf16*)ws;                                       // 2304*768*2 = 3,538,944
    unsigned long long* bits = (unsigned long long*)(ws + 3538944);
    bf16* hsb = (bf16*)(ws + 3538944 + 5529600);                 // 23296*768*2 = 35,782,656
    bf16* qg  = (bf16*)(ws + 3538944 + 5529600 + 35782656);      // 1536*176*64*2 = 34,603,008

    prep<<<dim3(CVT_BLOCKS + ROCR * NBS), 256, 0, stream>>>(hs, Wq, Wk, Wv, adj, hsb, Wb2, bits);
    fused_qkv_attn<<<dim3(NBS * NH), 256, 0, stream>>>(hsb, Wb2, bq, bk, bv, amask, bits, qg, out);
}

// Round 15
// 224.734 us; speedup vs baseline: 2.4595x; 2.4595x over previous
//
#include <hip/hip_runtime.h>
#include <hip/hip_bf16.h>

// Problem constants
#define NBS   128
#define NF    182      // 20 text + 150 ocr/obj + 12 decode
#define NP    192      // padded N for MFMA tiling
#define DMODEL 768
#define NH    12
#define HDIM  64
#define SEQT  20
#define ROCR  150

typedef __attribute__((ext_vector_type(4))) float  f32x4;
typedef __attribute__((ext_vector_type(8))) short  s16x8;
typedef __attribute__((ext_vector_type(4))) unsigned int u32x4;
using bf16 = __hip_bfloat16;

#define SB()    __builtin_amdgcn_sched_barrier(0)
#define BAR()   __builtin_amdgcn_s_barrier()

// global->LDS direct copy, 16B per lane. LDS dest linear in lane (base+lane*16).
__device__ __forceinline__ void gload_lds16(const void* g, void* l) {
    auto gp = (const __attribute__((address_space(1))) unsigned int*)((unsigned long long)g);
    auto lp = (__attribute__((address_space(3))) unsigned int*)(unsigned int)((unsigned long long)l);
    __builtin_amdgcn_global_load_lds(gp, lp, 16, 0, 0);
}

// ---------------------------------------------------------------------------
// Kernel 0: PREP (convert + pack_adj merged).
// Blocks [0, 9600): fp32->bf16: hs -> hsb; Wq|Wk|Wv -> Wb2 per-head layout
//   (Wb2 row R = h*192 + which*64 + r0 holds W_which[h*64+r0][:]).
// Blocks [9600, 28800): pack spatial adjacency -> bitmask (b,12,150,3).
// ---------------------------------------------------------------------------
#define CVT_BLOCKS 9600
__global__ __launch_bounds__(256) void prep(
    const float* __restrict__ hs,
    const float* __restrict__ Wq, const float* __restrict__ Wk, const float* __restrict__ Wv,
    const float* __restrict__ adj,
    bf16* __restrict__ hsb, bf16* __restrict__ Wb2,
    unsigned long long* __restrict__ bits)
{
    __shared__ float tile[ROCR * NH];       // used by pack branch only
    if (blockIdx.x < CVT_BLOCKS) {
        const size_t HT = (size_t)NBS * NF * DMODEL / 8;        // 2,236,416
        const size_t WT = 3ull * DMODEL * DMODEL / 8;           // 221,184
        size_t i = (size_t)blockIdx.x * 256 + threadIdx.x;
        if (i >= HT + WT) return;
        const float* src; bf16* dst;
        if (i < HT) {
            size_t e = i * 8; src = hs + e; dst = hsb + e;
        } else {
            size_t e = (i - HT) * 8;
            int R = (int)(e / DMODEL), c = (int)(e % DMODEL);
            int h = R / 192, t2 = (R % 192) / 64, r0 = R % 64;
            src = (t2 == 0 ? Wq : t2 == 1 ? Wk : Wv) + (size_t)(h * 64 + r0) * DMODEL + c;
            dst = Wb2 + e;
        }
        float4 a = *reinterpret_cast<const float4*>(src);
        float4 b = *reinterpret_cast<const float4*>(src + 4);
        union { s16x8 v; bf16 h8[8]; } u;
        u.h8[0] = __float2bfloat16(a.x); u.h8[1] = __float2bfloat16(a.y);
        u.h8[2] = __float2bfloat16(a.z); u.h8[3] = __float2bfloat16(a.w);
        u.h8[4] = __float2bfloat16(b.x); u.h8[5] = __float2bfloat16(b.y);
        u.h8[6] = __float2bfloat16(b.z); u.h8[7] = __float2bfloat16(b.w);
        *reinterpret_cast<s16x8*>(dst) = u.v;
    } else {
        const int pb = blockIdx.x - CVT_BLOCKS;
        const int b = pb / ROCR, r = pb - b * ROCR;
        const int tid = threadIdx.x, lane = tid & 63, w = tid >> 6;
        const float* src = adj + ((size_t)b * ROCR + r) * (ROCR * NH);
        for (int i = tid; i < ROCR * NH; i += 256) tile[i] = src[i];
        __syncthreads();
        for (int c = w; c < NH * 3; c += 4) {
            int hh = c / 3, wd = c - hh * 3;
            int k = wd * 64 + lane;
            int j = k - SEQT;
            bool v = false;
            if (j >= 0 && j < ROCR) v = (tile[j * NH + hh] > 0.5f);
            unsigned long long m = __ballot(v);
            if (lane == 0) bits[(((size_t)b * NH + hh) * ROCR + r) * 3 + wd] = m;
        }
    }
}

// ---------------------------------------------------------------------------
// Kernel 2: FUSED per-(b,h) QKV-projection + attention.
// R14 body with the spill bug fixed: __launch_bounds__(256, 2) — the (256,3)
// cap (~170 VGPR) forced the 144-reg acc to scratch (VGPR 84, 1.3GB scratch
// writes, 3.3x slowdown). At (256,2) VGPR=~120 (R13-measured, no spill) and
// occupancy is LDS-limited: 53.4KB x 3 = 160.2KB <= 160KiB -> 3 blocks/CU.
// Q transits through GLOBAL qg (single-pass epilogue -> acc dies at once);
// attention = R12/R13-verified in-register-P body.
// LDS map:
//   [0..24576)      staging buf0 -> K[192][64] swz after GEMM
//   [24576..49152)  staging buf1 -> Vt[64][192] swz after GEMM
//   [49152..53376)  Lw bitmasks (176 x 3 u64);  [53376..53400) aw
// ---------------------------------------------------------------------------
#define KO2   0
#define VTO2  24576
#define LWO2  49152
#define AWO2  53376

__global__ __launch_bounds__(256, 2) void fused_qkv_attn(
    const bf16* __restrict__ hsb, const bf16* __restrict__ Wb2,
    const float* __restrict__ bq, const float* __restrict__ bk, const float* __restrict__ bv,
    const float* __restrict__ amask,
    const unsigned long long* __restrict__ bits,
    bf16* __restrict__ qg,
    float* __restrict__ out)
{
    __shared__ char L[53400];
    const int tid  = threadIdx.x;
    const int lane = tid & 63;
    const int wid  = tid >> 6;
    const int wr = wid >> 1, wc = wid & 1;      // 2x2 wave grid, 96x96 each
    const int lm = lane & 15, lg = lane >> 4;

    // m204 XCD chunking (1536 = 8*192): 12 head-blocks of one b on one XCD.
    const int flat = blockIdx.x;
    const int wgid = (flat & 7) * 192 + (flat >> 3);
    const int b = wgid / NH, h = wgid - b * NH;

    float* obase = out + (size_t)b * NF * DMODEL + h * HDIM;
    bf16*  qgb   = qg + (size_t)wgid * (176 * 64);

    // ---- masks + decode-row zeroing (independent of GEMM) ----
    if (wid == 0) {
        #pragma unroll
        for (int w = 0; w < 3; ++w) {
            int k = w * 64 + lane;
            bool v = (k < NF) && (amask[b * NF + k] == 0.0f);
            unsigned long long m = __ballot(v);
            if (lane == 0) ((unsigned long long*)(L + AWO2))[w] = m;
        }
    }
    for (int i = tid; i < 12 * 64; i += 256)
        obase[(size_t)(170 + (i >> 6)) * DMODEL + (i & 63)] = 0.f;
    __syncthreads();
    if (tid < 176) {
        int r = tid;
        unsigned long long s0 = 0, s1 = 0, s2 = 0;
        const unsigned long long DEC = 0xFFFull << 42;      // keys 170..181
        if (r < SEQT) {
            s2 = DEC;
        } else if (r < SEQT + ROCR) {
            const unsigned long long* bp = bits + (((size_t)b * NH + h) * ROCR + (r - SEQT)) * 3;
            s0 = bp[0]; s1 = bp[1]; s2 = bp[2] | DEC;
        }
        unsigned long long* aw = (unsigned long long*)(L + AWO2);
        unsigned long long* Lw = (unsigned long long*)(L + LWO2);
        Lw[r * 3 + 0] = s0 & aw[0];
        Lw[r * 3 + 1] = s1 & aw[1];
        Lw[r * 3 + 2] = s2 & aw[2];
    }

    // ---- Phase G: GEMM (verified BK=32 dbuf, counted vmcnt(6)) ----
    const char* gA = (const char*)(hsb + (size_t)b * NF * DMODEL);   // 192 rows (pad rows harmless)
    const char* gW = (const char*)(Wb2 + (size_t)h * 192 * DMODEL);

    f32x4 acc[6][6];
    #pragma unroll
    for (int i = 0; i < 6; ++i)
        #pragma unroll
        for (int j = 0; j < 6; ++j) acc[i][j] = (f32x4){0.f, 0.f, 0.f, 0.f};

    const int srow4 = tid >> 2, sch4 = tid & 3;

    auto ST = [&](int kt, int bsel) {
        char* dA = L + bsel * 24576;
        char* dW = dA + 12288;
        #pragma unroll
        for (int it = 0; it < 3; ++it) {
            int row = it * 64 + srow4;
            int lc = sch4 ^ ((row >> 1) & 3);
            size_t go = (size_t)row * 1536 + (size_t)kt * 64 + lc * 16;
            int o = row * 64 + sch4 * 16;
            gload_lds16(gA + go, dA + o);
            gload_lds16(gW + go, dW + o);
        }
    };
    auto CP = [&](int bsel) {
        const char* Ab = L + bsel * 24576;
        const char* Wp = Ab + 12288;
        s16x8 af[6], bf6[6];
        #pragma unroll
        for (int mi = 0; mi < 6; ++mi) {
            int r = 96 * wr + 16 * mi + lm;
            af[mi] = *reinterpret_cast<const s16x8*>(Ab + r * 64 + ((lg ^ ((r >> 1) & 3)) << 4));
        }
        #pragma unroll
        for (int ni = 0; ni < 6; ++ni) {
            int r = 96 * wc + 16 * ni + lm;
            bf6[ni] = *reinterpret_cast<const s16x8*>(Wp + r * 64 + ((lg ^ ((r >> 1) & 3)) << 4));
        }
        __builtin_amdgcn_s_setprio(1);
        #pragma unroll
        for (int mi = 0; mi < 6; ++mi)
            #pragma unroll
            for (int ni = 0; ni < 6; ++ni)
                acc[mi][ni] = __builtin_amdgcn_mfma_f32_16x16x32_bf16(af[mi], bf6[ni], acc[mi][ni], 0, 0, 0);
        __builtin_amdgcn_s_setprio(0);
    };

    ST(0, 0);
    ST(1, 1);
    for (int t = 0; t < 24; ++t) {
        if (t < 23) { asm volatile("s_waitcnt vmcnt(6)" ::: "memory"); }
        else        { asm volatile("s_waitcnt vmcnt(0)" ::: "memory"); }
        SB(); BAR(); SB();
        CP(t & 1);
        SB(); BAR();
        if (t + 2 < 24) ST(t + 2, t & 1);
    }
    BAR();   // all CP reads done before epilogue overwrites staging region

    // ---- epilogue (SINGLE PASS): acc+bias -> Q global / K LDS / Vt LDS ----
    float bias6[6];
    #pragma unroll
    for (int ni = 0; ni < 6; ++ni) {
        int c = 96 * wc + 16 * ni + lm;
        int whichc = c >> 6, cc = c & 63;
        const float* bp = (whichc == 0) ? bq : (whichc == 1) ? bk : bv;
        bias6[ni] = bp[h * 64 + cc];
    }
    #pragma unroll
    for (int mi = 0; mi < 6; ++mi) {
        #pragma unroll
        for (int ni = 0; ni < 6; ++ni) {
            int c = 96 * wc + 16 * ni + lm;
            #pragma unroll
            for (int j = 0; j < 4; ++j) {
                int row = 96 * wr + 16 * mi + 4 * lg + j;
                bf16 hv = __float2bfloat16(acc[mi][ni][j] + bias6[ni]);
                unsigned short us = *reinterpret_cast<unsigned short*>(&hv);
                if (c < 64) {
                    if (row < 176) qgb[row * 64 + c] = hv;
                } else if (c < 128) {
                    int cc = c - 64;
                    *reinterpret_cast<unsigned short*>(L + KO2 + row * 128 + ((2 * cc) ^ ((row & 7) << 4))) = us;
                } else if (row < NF) {
                    int d = c - 128;
                    *reinterpret_cast<unsigned short*>(L + VTO2 + d * 384 + ((2 * row) ^ ((d & 7) << 4))) = us;
                }
            }
        }
    }
    // zero Vt pad keys 182..191 (NaN containment)
    for (int i = tid; i < 64 * 10; i += 256) {
        int d = i / 10, k2 = NF + (i - d * 10);
        *reinterpret_cast<unsigned short*>(L + VTO2 + d * 384 + ((2 * k2) ^ ((d & 7) << 4))) = 0;
    }
    __syncthreads();    // drains vmcnt+lgkm: Q global writes + K/Vt LDS visible

    // ---- Q-preload from global (L2-hot, block-private region) ----
    s16x8 qf[3][2];
    #pragma unroll
    for (int bi = 0; bi < 3; ++bi) {
        int band = wid + 4 * bi;
        int qrow = ((band < 11) ? band * 16 : 0) + lm;      // safe dummy for band>=11
        const bf16* qb = qgb + qrow * 64;
        qf[bi][0] = *reinterpret_cast<const s16x8*>(qb + lg * 8);
        qf[bi][1] = *reinterpret_cast<const s16x8*>(qb + 32 + lg * 8);
    }

    // ---- Phase A: attention, P fully in-register (R12/R13-verified body) ----
    const unsigned long long* LwA = (const unsigned long long*)(L + LWO2);

    #pragma unroll
    for (int bi = 0; bi < 3; ++bi) {
        const int band = wid + 4 * bi;
        if (band >= 11) continue;
        const int q0 = band * 16;

        // masks for this lane's q-row (qrow = q0 + lm)
        const unsigned long long* lwp = LwA + (q0 + lm) * 3;
        unsigned long long mw0 = lwp[0], mw1 = lwp[1], mw2 = lwp[2];

        // swapped QK^T: sacc[t][j] = S[key=16t+4lg+j][qrow=q0+lm]
        f32x4 sacc[12];
        #pragma unroll
        for (int t = 0; t < 12; ++t) sacc[t] = (f32x4){0.f, 0.f, 0.f, 0.f};
        #pragma unroll
        for (int t = 0; t < 12; ++t) {
            int key = t * 16 + lm;
            const char* kb = L + KO2 + key * 128;
            int sw = (key & 7) << 4;
            s16x8 kf0 = *reinterpret_cast<const s16x8*>(kb + ((lg * 16) ^ sw));
            s16x8 kf1 = *reinterpret_cast<const s16x8*>(kb + ((64 + lg * 16) ^ sw));
            sacc[t] = __builtin_amdgcn_mfma_f32_16x16x32_bf16(kf0, qf[bi][0], sacc[t], 0, 0, 0);
            sacc[t] = __builtin_amdgcn_mfma_f32_16x16x32_bf16(kf1, qf[bi][1], sacc[t], 0, 0, 0);
        }

        // mask + per-lane softmax (this lane owns one q-row)
        float mx = -3.0e38f;
        #pragma unroll
        for (int t = 0; t < 12; ++t) {
            unsigned long long w = (t < 4) ? mw0 : (t < 8) ? mw1 : mw2;
            #pragma unroll
            for (int j = 0; j < 4; ++j) {
                int sh = ((t & 3) << 4) + 4 * lg + j;
                float s = sacc[t][j] * 0.125f;
                s = ((w >> sh) & 1ull) ? s : -3.0e38f;
                sacc[t][j] = s;
                mx = fmaxf(mx, s);
            }
        }
        mx = fmaxf(mx, __shfl_xor(mx, 16));
        mx = fmaxf(mx, __shfl_xor(mx, 32));
        float sum = 0.f;
        #pragma unroll
        for (int t = 0; t < 12; ++t)
            #pragma unroll
            for (int j = 0; j < 4; ++j) {
                float e = (sacc[t][j] > -1.0e37f) ? __expf(sacc[t][j] - mx) : 0.f;
                sacc[t][j] = e;
                sum += e;
            }
        sum += __shfl_xor(sum, 16);
        sum += __shfl_xor(sum, 32);
        float scl = (mx > -1.0e37f) ? 1.0f / sum : 0.f;

        // pack P rows to bf16 dword pairs per tile
        unsigned int p0[12], p1[12];
        #pragma unroll
        for (int t = 0; t < 12; ++t) {
            bf16 b0 = __float2bfloat16(sacc[t][0] * scl);
            bf16 b1 = __float2bfloat16(sacc[t][1] * scl);
            bf16 b2 = __float2bfloat16(sacc[t][2] * scl);
            bf16 b3 = __float2bfloat16(sacc[t][3] * scl);
            p0[t] = (unsigned int)*reinterpret_cast<unsigned short*>(&b0)
                  | ((unsigned int)*reinterpret_cast<unsigned short*>(&b1) << 16);
            p1[t] = (unsigned int)*reinterpret_cast<unsigned short*>(&b2)
                  | ((unsigned int)*reinterpret_cast<unsigned short*>(&b3) << 16);
        }

        // PV: build A-frags by lane exchange; dest (lg,ks) = keys 32ks+8lg+0..7
        f32x4 oacc[4];
        #pragma unroll
        for (int t = 0; t < 4; ++t) oacc[t] = (f32x4){0.f, 0.f, 0.f, 0.f};
        const bool hi = (lg & 1);
        #pragma unroll
        for (int ks = 0; ks < 6; ++ks) {
            unsigned int A0 = p0[2 * ks],     A1 = p1[2 * ks];
            unsigned int B0 = p0[2 * ks + 1], B1 = p1[2 * ks + 1];
            unsigned int u0 = __shfl_xor(A0, 16), u1 = __shfl_xor(A1, 16);
            unsigned int v0 = __shfl_xor(B0, 16), v1 = __shfl_xor(B1, 16);
            unsigned int hA0 = hi ? u0 : A0, hA1 = hi ? u1 : A1;
            unsigned int hA2 = hi ? A0 : u0, hA3 = hi ? A1 : u1;
            unsigned int hB0 = hi ? v0 : B0, hB1 = hi ? v1 : B1;
            unsigned int hB2 = hi ? B0 : v0, hB3 = hi ? B1 : v1;
            unsigned int xA0 = __shfl_xor(hA0, 32), xA1 = __shfl_xor(hA1, 32);
            unsigned int xA2 = __shfl_xor(hA2, 32), xA3 = __shfl_xor(hA3, 32);
            unsigned int xB0 = __shfl_xor(hB0, 32), xB1 = __shfl_xor(hB1, 32);
            unsigned int xB2 = __shfl_xor(hB2, 32), xB3 = __shfl_xor(hB3, 32);
            u32x4 f;
            if (lg == 0)      f = (u32x4){hA0, hA1, hA2, hA3};
            else if (lg == 1) f = (u32x4){xA0, xA1, xA2, xA3};
            else if (lg == 2) f = (u32x4){xB0, xB1, xB2, xB3};
            else              f = (u32x4){hB0, hB1, hB2, hB3};
            s16x8 pa;
            __builtin_memcpy(&pa, &f, 16);
            #pragma unroll
            for (int t2 = 0; t2 < 4; ++t2) {
                int d = t2 * 16 + lm;
                s16x8 vf = *reinterpret_cast<const s16x8*>(L + VTO2 + d * 384 + ((ks * 64 + lg * 16) ^ ((d & 7) << 4)));
                oacc[t2] = __builtin_amdgcn_mfma_f32_16x16x32_bf16(pa, vf, oacc[t2], 0, 0, 0);
            }
        }
        #pragma unroll
        for (int j = 0; j < 4; ++j) {
            int row = q0 + lg * 4 + j;
            if (row < 170) {
                #pragma unroll
                for (int t2 = 0; t2 < 4; ++t2)
                    obase[(size_t)row * DMODEL + t2 * 16 + lm] = oacc[t2][j];
            }
        }
    }
}

// ---------------------------------------------------------------------------
extern "C" void kernel_launch(void* const* d_in, const int* in_sizes, int n_in,
                              void* d_out, int out_size, void* d_ws, size_t ws_size,
                              hipStream_t stream)
{
    const float* hs    = (const float*)d_in[0];
    const float* amask = (const float*)d_in[1];
    const float* adj   = (const float*)d_in[2];
    const float* Wq    = (const float*)d_in[3];
    const float* bq    = (const float*)d_in[4];
    const float* Wk    = (const float*)d_in[5];
    const float* bk    = (const float*)d_in[6];
    const float* Wv    = (const float*)d_in[7];
    const float* bv    = (const float*)d_in[8];
    float* out = (float*)d_out;

    // workspace: Wb2 (3.54MB) | bits (5.53MB) | hsb (35.8MB) | qg (34.6MB)
    // (qg after hsb also provides the pad-row read slack for b=127)
    char* ws = (char*)d_ws;
    bf16* Wb2 = (bf16*)ws;                                       // 2304*768*2 = 3,538,944
    unsigned long long* bits = (unsigned long long*)(ws + 3538944);
    bf16* hsb = (bf16*)(ws + 3538944 + 5529600);                 // 23296*768*2 = 35,782,656
    bf16* qg  = (bf16*)(ws + 3538944 + 5529600 + 35782656);      // 1536*176*64*2 = 34,603,008

    prep<<<dim3(CVT_BLOCKS + ROCR * NBS), 256, 0, stream>>>(hs, Wq, Wk, Wv, adj, hsb, Wb2, bits);
    fused_qkv_attn<<<dim3(NBS * NH), 256, 0, stream>>>(hsb, Wb2, bq, bk, bv, amask, bits, qg, out);
}

// Round 16
// 220.381 us; speedup vs baseline: 2.5081x; 1.0198x over previous
//
#include <hip/hip_runtime.h>
#include <hip/hip_bf16.h>

// Problem constants
#define NBS   128
#define NF    182      // 20 text + 150 ocr/obj + 12 decode
#define NP    192      // padded N for MFMA tiling
#define DMODEL 768
#define NH    12
#define HDIM  64
#define SEQT  20
#define ROCR  150

typedef __attribute__((ext_vector_type(4))) float  f32x4;
typedef __attribute__((ext_vector_type(8))) short  s16x8;
typedef __attribute__((ext_vector_type(4))) unsigned int u32x4;
using bf16 = __hip_bfloat16;

#define SB()    __builtin_amdgcn_sched_barrier(0)
#define BAR()   __builtin_amdgcn_s_barrier()

// global->LDS direct copy, 16B per lane. LDS dest linear in lane (base+lane*16).
__device__ __forceinline__ void gload_lds16(const void* g, void* l) {
    auto gp = (const __attribute__((address_space(1))) unsigned int*)((unsigned long long)g);
    auto lp = (__attribute__((address_space(3))) unsigned int*)(unsigned int)((unsigned long long)l);
    __builtin_amdgcn_global_load_lds(gp, lp, 16, 0, 0);
}

// ---------------------------------------------------------------------------
// Kernel 0: PREP (convert + pack_adj merged).
// Blocks [0, 9600): fp32->bf16: hs -> hsb; Wq|Wk|Wv -> Wb2 per-head layout
//   (Wb2 row R = h*192 + which*64 + r0 holds W_which[h*64+r0][:]).
// Blocks [9600, 28800): pack spatial adjacency -> bitmask (b,12,150,3).
// ---------------------------------------------------------------------------
#define CVT_BLOCKS 9600
__global__ __launch_bounds__(256) void prep(
    const float* __restrict__ hs,
    const float* __restrict__ Wq, const float* __restrict__ Wk, const float* __restrict__ Wv,
    const float* __restrict__ adj,
    bf16* __restrict__ hsb, bf16* __restrict__ Wb2,
    unsigned long long* __restrict__ bits)
{
    __shared__ float tile[ROCR * NH];       // used by pack branch only
    if (blockIdx.x < CVT_BLOCKS) {
        const size_t HT = (size_t)NBS * NF * DMODEL / 8;        // 2,236,416
        const size_t WT = 3ull * DMODEL * DMODEL / 8;           // 221,184
        size_t i = (size_t)blockIdx.x * 256 + threadIdx.x;
        if (i >= HT + WT) return;
        const float* src; bf16* dst;
        if (i < HT) {
            size_t e = i * 8; src = hs + e; dst = hsb + e;
        } else {
            size_t e = (i - HT) * 8;
            int R = (int)(e / DMODEL), c = (int)(e % DMODEL);
            int h = R / 192, t2 = (R % 192) / 64, r0 = R % 64;
            src = (t2 == 0 ? Wq : t2 == 1 ? Wk : Wv) + (size_t)(h * 64 + r0) * DMODEL + c;
            dst = Wb2 + e;
        }
        float4 a = *reinterpret_cast<const float4*>(src);
        float4 b = *reinterpret_cast<const float4*>(src + 4);
        union { s16x8 v; bf16 h8[8]; } u;
        u.h8[0] = __float2bfloat16(a.x); u.h8[1] = __float2bfloat16(a.y);
        u.h8[2] = __float2bfloat16(a.z); u.h8[3] = __float2bfloat16(a.w);
        u.h8[4] = __float2bfloat16(b.x); u.h8[5] = __float2bfloat16(b.y);
        u.h8[6] = __float2bfloat16(b.z); u.h8[7] = __float2bfloat16(b.w);
        *reinterpret_cast<s16x8*>(dst) = u.v;
    } else {
        const int pb = blockIdx.x - CVT_BLOCKS;
        const int b = pb / ROCR, r = pb - b * ROCR;
        const int tid = threadIdx.x, lane = tid & 63, w = tid >> 6;
        const float* src = adj + ((size_t)b * ROCR + r) * (ROCR * NH);
        for (int i = tid; i < ROCR * NH; i += 256) tile[i] = src[i];
        __syncthreads();
        for (int c = w; c < NH * 3; c += 4) {
            int hh = c / 3, wd = c - hh * 3;
            int k = wd * 64 + lane;
            int j = k - SEQT;
            bool v = false;
            if (j >= 0 && j < ROCR) v = (tile[j * NH + hh] > 0.5f);
            unsigned long long m = __ballot(v);
            if (lane == 0) bits[(((size_t)b * NH + hh) * ROCR + r) * 3 + wd] = m;
        }
    }
}

// ---------------------------------------------------------------------------
// Kernel 2: FUSED per-(b,h) QKV-projection + attention.
// R15 body with masks moved OUT of LDS: aw = per-wave ballot registers;
// per-row words loaded straight from global `bits` in the attention loop.
// LDS = exactly 49152 B (K 24KB + Vt 24KB aliased over staging dbuf) ->
// 3 x 49152 = 147456 <= 160K: 3 blocks/CU guaranteed (R15's 53.8KB left
// only 2.5KB margin and the 3rd block never landed -> occupancy stuck 20%).
// __launch_bounds__(256,2): no VGPR cap (R14's (256,3) caused acc spill).
// LDS map:
//   [0..24576)      staging buf0 -> K[192][64] swz after GEMM
//   [24576..49152)  staging buf1 -> Vt[64][192] swz after GEMM
// ---------------------------------------------------------------------------
#define KO2   0
#define VTO2  24576

__global__ __launch_bounds__(256, 2) void fused_qkv_attn(
    const bf16* __restrict__ hsb, const bf16* __restrict__ Wb2,
    const float* __restrict__ bq, const float* __restrict__ bk, const float* __restrict__ bv,
    const float* __restrict__ amask,
    const unsigned long long* __restrict__ bits,
    bf16* __restrict__ qg,
    float* __restrict__ out)
{
    __shared__ char L[49152];
    const int tid  = threadIdx.x;
    const int lane = tid & 63;
    const int wid  = tid >> 6;
    const int wr = wid >> 1, wc = wid & 1;      // 2x2 wave grid, 96x96 each
    const int lm = lane & 15, lg = lane >> 4;

    // m204 XCD chunking (1536 = 8*192): 12 head-blocks of one b on one XCD.
    const int flat = blockIdx.x;
    const int wgid = (flat & 7) * 192 + (flat >> 3);
    const int b = wgid / NH, h = wgid - b * NH;

    float* obase = out + (size_t)b * NF * DMODEL + h * HDIM;
    bf16*  qgb   = qg + (size_t)wgid * (176 * 64);

    // ---- aw: amask ballot words, per-wave registers (no LDS, no sync) ----
    unsigned long long aw0, aw1, aw2;
    {
        int k0 = lane, k1 = 64 + lane, k2 = 128 + lane;
        aw0 = __ballot(amask[b * NF + k0] == 0.0f);
        aw1 = __ballot(amask[b * NF + k1] == 0.0f);
        aw2 = __ballot((k2 < NF) && (amask[b * NF + k2] == 0.0f));
    }
    // decode output rows are exactly zero
    for (int i = tid; i < 12 * 64; i += 256)
        obase[(size_t)(170 + (i >> 6)) * DMODEL + (i & 63)] = 0.f;

    // ---- Phase G: GEMM (verified BK=32 dbuf, counted vmcnt(6)) ----
    const char* gA = (const char*)(hsb + (size_t)b * NF * DMODEL);   // 192 rows (pad rows harmless)
    const char* gW = (const char*)(Wb2 + (size_t)h * 192 * DMODEL);

    f32x4 acc[6][6];
    #pragma unroll
    for (int i = 0; i < 6; ++i)
        #pragma unroll
        for (int j = 0; j < 6; ++j) acc[i][j] = (f32x4){0.f, 0.f, 0.f, 0.f};

    const int srow4 = tid >> 2, sch4 = tid & 3;

    auto ST = [&](int kt, int bsel) {
        char* dA = L + bsel * 24576;
        char* dW = dA + 12288;
        #pragma unroll
        for (int it = 0; it < 3; ++it) {
            int row = it * 64 + srow4;
            int lc = sch4 ^ ((row >> 1) & 3);
            size_t go = (size_t)row * 1536 + (size_t)kt * 64 + lc * 16;
            int o = row * 64 + sch4 * 16;
            gload_lds16(gA + go, dA + o);
            gload_lds16(gW + go, dW + o);
        }
    };
    auto CP = [&](int bsel) {
        const char* Ab = L + bsel * 24576;
        const char* Wp = Ab + 12288;
        s16x8 af[6], bf6[6];
        #pragma unroll
        for (int mi = 0; mi < 6; ++mi) {
            int r = 96 * wr + 16 * mi + lm;
            af[mi] = *reinterpret_cast<const s16x8*>(Ab + r * 64 + ((lg ^ ((r >> 1) & 3)) << 4));
        }
        #pragma unroll
        for (int ni = 0; ni < 6; ++ni) {
            int r = 96 * wc + 16 * ni + lm;
            bf6[ni] = *reinterpret_cast<const s16x8*>(Wp + r * 64 + ((lg ^ ((r >> 1) & 3)) << 4));
        }
        __builtin_amdgcn_s_setprio(1);
        #pragma unroll
        for (int mi = 0; mi < 6; ++mi)
            #pragma unroll
            for (int ni = 0; ni < 6; ++ni)
                acc[mi][ni] = __builtin_amdgcn_mfma_f32_16x16x32_bf16(af[mi], bf6[ni], acc[mi][ni], 0, 0, 0);
        __builtin_amdgcn_s_setprio(0);
    };

    ST(0, 0);
    ST(1, 1);
    for (int t = 0; t < 24; ++t) {
        if (t < 23) { asm volatile("s_waitcnt vmcnt(6)" ::: "memory"); }
        else        { asm volatile("s_waitcnt vmcnt(0)" ::: "memory"); }
        SB(); BAR(); SB();
        CP(t & 1);
        SB(); BAR();
        if (t + 2 < 24) ST(t + 2, t & 1);
    }
    BAR();   // all CP reads done before epilogue overwrites staging region

    // ---- epilogue (SINGLE PASS): acc+bias -> Q global / K LDS / Vt LDS ----
    float bias6[6];
    #pragma unroll
    for (int ni = 0; ni < 6; ++ni) {
        int c = 96 * wc + 16 * ni + lm;
        int whichc = c >> 6, cc = c & 63;
        const float* bp = (whichc == 0) ? bq : (whichc == 1) ? bk : bv;
        bias6[ni] = bp[h * 64 + cc];
    }
    #pragma unroll
    for (int mi = 0; mi < 6; ++mi) {
        #pragma unroll
        for (int ni = 0; ni < 6; ++ni) {
            int c = 96 * wc + 16 * ni + lm;
            #pragma unroll
            for (int j = 0; j < 4; ++j) {
                int row = 96 * wr + 16 * mi + 4 * lg + j;
                bf16 hv = __float2bfloat16(acc[mi][ni][j] + bias6[ni]);
                unsigned short us = *reinterpret_cast<unsigned short*>(&hv);
                if (c < 64) {
                    if (row < 176) qgb[row * 64 + c] = hv;
                } else if (c < 128) {
                    int cc = c - 64;
                    *reinterpret_cast<unsigned short*>(L + KO2 + row * 128 + ((2 * cc) ^ ((row & 7) << 4))) = us;
                } else if (row < NF) {
                    int d = c - 128;
                    *reinterpret_cast<unsigned short*>(L + VTO2 + d * 384 + ((2 * row) ^ ((d & 7) << 4))) = us;
                }
            }
        }
    }
    // zero Vt pad keys 182..191 (NaN containment)
    for (int i = tid; i < 64 * 10; i += 256) {
        int d = i / 10, k2 = NF + (i - d * 10);
        *reinterpret_cast<unsigned short*>(L + VTO2 + d * 384 + ((2 * k2) ^ ((d & 7) << 4))) = 0;
    }
    __syncthreads();    // drains vmcnt+lgkm: Q global writes + K/Vt LDS visible

    // ---- Q-preload from global (L2-hot, block-private region) ----
    s16x8 qf[3][2];
    #pragma unroll
    for (int bi = 0; bi < 3; ++bi) {
        int band = wid + 4 * bi;
        int qrow = ((band < 11) ? band * 16 : 0) + lm;      // safe dummy for band>=11
        const bf16* qb = qgb + qrow * 64;
        qf[bi][0] = *reinterpret_cast<const s16x8*>(qb + lg * 8);
        qf[bi][1] = *reinterpret_cast<const s16x8*>(qb + 32 + lg * 8);
    }

    // ---- Phase A: attention, P fully in-register (verified body) ----
    const unsigned long long* bbase = bits + ((size_t)b * NH + h) * ROCR * 3;
    const unsigned long long DEC = 0xFFFull << 42;          // keys 170..181

    #pragma unroll
    for (int bi = 0; bi < 3; ++bi) {
        const int band = wid + 4 * bi;
        if (band >= 11) continue;
        const int q0 = band * 16;

        // masks for this lane's q-row, straight from global bits (L2-hot)
        const int qrow = q0 + lm;
        unsigned long long mw0, mw1, mw2;
        if (qrow < SEQT) {
            mw0 = 0; mw1 = 0; mw2 = DEC & aw2;
        } else {
            const unsigned long long* bp = bbase + (size_t)(qrow - SEQT) * 3;
            mw0 = bp[0] & aw0;
            mw1 = bp[1] & aw1;
            mw2 = (bp[2] | DEC) & aw2;
        }

        // swapped QK^T: sacc[t][j] = S[key=16t+4lg+j][qrow=q0+lm]
        f32x4 sacc[12];
        #pragma unroll
        for (int t = 0; t < 12; ++t) sacc[t] = (f32x4){0.f, 0.f, 0.f, 0.f};
        #pragma unroll
        for (int t = 0; t < 12; ++t) {
            int key = t * 16 + lm;
            const char* kb = L + KO2 + key * 128;
            int sw = (key & 7) << 4;
            s16x8 kf0 = *reinterpret_cast<const s16x8*>(kb + ((lg * 16) ^ sw));
            s16x8 kf1 = *reinterpret_cast<const s16x8*>(kb + ((64 + lg * 16) ^ sw));
            sacc[t] = __builtin_amdgcn_mfma_f32_16x16x32_bf16(kf0, qf[bi][0], sacc[t], 0, 0, 0);
            sacc[t] = __builtin_amdgcn_mfma_f32_16x16x32_bf16(kf1, qf[bi][1], sacc[t], 0, 0, 0);
        }

        // mask + per-lane softmax (this lane owns one q-row)
        float mx = -3.0e38f;
        #pragma unroll
        for (int t = 0; t < 12; ++t) {
            unsigned long long w = (t < 4) ? mw0 : (t < 8) ? mw1 : mw2;
            #pragma unroll
            for (int j = 0; j < 4; ++j) {
                int sh = ((t & 3) << 4) + 4 * lg + j;
                float s = sacc[t][j] * 0.125f;
                s = ((w >> sh) & 1ull) ? s : -3.0e38f;
                sacc[t][j] = s;
                mx = fmaxf(mx, s);
            }
        }
        mx = fmaxf(mx, __shfl_xor(mx, 16));
        mx = fmaxf(mx, __shfl_xor(mx, 32));
        float sum = 0.f;
        #pragma unroll
        for (int t = 0; t < 12; ++t)
            #pragma unroll
            for (int j = 0; j < 4; ++j) {
                float e = (sacc[t][j] > -1.0e37f) ? __expf(sacc[t][j] - mx) : 0.f;
                sacc[t][j] = e;
                sum += e;
            }
        sum += __shfl_xor(sum, 16);
        sum += __shfl_xor(sum, 32);
        float scl = (mx > -1.0e37f) ? 1.0f / sum : 0.f;

        // pack P rows to bf16 dword pairs per tile
        unsigned int p0[12], p1[12];
        #pragma unroll
        for (int t = 0; t < 12; ++t) {
            bf16 b0 = __float2bfloat16(sacc[t][0] * scl);
            bf16 b1 = __float2bfloat16(sacc[t][1] * scl);
            bf16 b2 = __float2bfloat16(sacc[t][2] * scl);
            bf16 b3 = __float2bfloat16(sacc[t][3] * scl);
            p0[t] = (unsigned int)*reinterpret_cast<unsigned short*>(&b0)
                  | ((unsigned int)*reinterpret_cast<unsigned short*>(&b1) << 16);
            p1[t] = (unsigned int)*reinterpret_cast<unsigned short*>(&b2)
                  | ((unsigned int)*reinterpret_cast<unsigned short*>(&b3) << 16);
        }

        // PV: build A-frags by lane exchange; dest (lg,ks) = keys 32ks+8lg+0..7
        f32x4 oacc[4];
        #pragma unroll
        for (int t = 0; t < 4; ++t) oacc[t] = (f32x4){0.f, 0.f, 0.f, 0.f};
        const bool hi = (lg & 1);
        #pragma unroll
        for (int ks = 0; ks < 6; ++ks) {
            unsigned int A0 = p0[2 * ks],     A1 = p1[2 * ks];
            unsigned int B0 = p0[2 * ks + 1], B1 = p1[2 * ks + 1];
            unsigned int u0 = __shfl_xor(A0, 16), u1 = __shfl_xor(A1, 16);
            unsigned int v0 = __shfl_xor(B0, 16), v1 = __shfl_xor(B1, 16);
            unsigned int hA0 = hi ? u0 : A0, hA1 = hi ? u1 : A1;
            unsigned int hA2 = hi ? A0 : u0, hA3 = hi ? A1 : u1;
            unsigned int hB0 = hi ? v0 : B0, hB1 = hi ? v1 : B1;
            unsigned int hB2 = hi ? B0 : v0, hB3 = hi ? B1 : v1;
            unsigned int xA0 = __shfl_xor(hA0, 32), xA1 = __shfl_xor(hA1, 32);
            unsigned int xA2 = __shfl_xor(hA2, 32), xA3 = __shfl_xor(hA3, 32);
            unsigned int xB0 = __shfl_xor(hB0, 32), xB1 = __shfl_xor(hB1, 32);
            unsigned int xB2 = __shfl_xor(hB2, 32), xB3 = __shfl_xor(hB3, 32);
            u32x4 f;
            if (lg == 0)      f = (u32x4){hA0, hA1, hA2, hA3};
            else if (lg == 1) f = (u32x4){xA0, xA1, xA2, xA3};
            else if (lg == 2) f = (u32x4){xB0, xB1, xB2, xB3};
            else              f = (u32x4){hB0, hB1, hB2, hB3};
            s16x8 pa;
            __builtin_memcpy(&pa, &f, 16);
            #pragma unroll
            for (int t2 = 0; t2 < 4; ++t2) {
                int d = t2 * 16 + lm;
                s16x8 vf = *reinterpret_cast<const s16x8*>(L + VTO2 + d * 384 + ((ks * 64 + lg * 16) ^ ((d & 7) << 4)));
                oacc[t2] = __builtin_amdgcn_mfma_f32_16x16x32_bf16(pa, vf, oacc[t2], 0, 0, 0);
            }
        }
        #pragma unroll
        for (int j = 0; j < 4; ++j) {
            int row = q0 + lg * 4 + j;
            if (row < 170) {
                #pragma unroll
                for (int t2 = 0; t2 < 4; ++t2)
                    obase[(size_t)row * DMODEL + t2 * 16 + lm] = oacc[t2][j];
            }
        }
    }
}

// ---------------------------------------------------------------------------
extern "C" void kernel_launch(void* const* d_in, const int* in_sizes, int n_in,
                              void* d_out, int out_size, void* d_ws, size_t ws_size,
                              hipStream_t stream)
{
    const float* hs    = (const float*)d_in[0];
    const float* amask = (const float*)d_in[1];
    const float* adj   = (const float*)d_in[2];
    const float* Wq    = (const float*)d_in[3];
    const float* bq    = (const float*)d_in[4];
    const float* Wk    = (const float*)d_in[5];
    const float* bk    = (const float*)d_in[6];
    const float* Wv    = (const float*)d_in[7];
    const float* bv    = (const float*)d_in[8];
    float* out = (float*)d_out;

    // workspace: Wb2 (3.54MB) | bits (5.53MB) | hsb (35.8MB) | qg (34.6MB)
    // (qg after hsb also provides the pad-row read slack for b=127)
    char* ws = (char*)d_ws;
    bf16* Wb2 = (bf16*)ws;                                       // 2304*768*2 = 3,538,944
    unsigned long long* bits = (unsigned long long*)(ws + 3538944);
    bf16* hsb = (bf16*)(ws + 3538944 + 5529600);                 // 23296*768*2 = 35,782,656
    bf16* qg  = (bf16*)(ws + 3538944 + 5529600 + 35782656);      // 1536*176*64*2 = 34,603,008

    prep<<<dim3(CVT_BLOCKS + ROCR * NBS), 256, 0, stream>>>(hs, Wq, Wk, Wv, adj, hsb, Wb2, bits);
    fused_qkv_attn<<<dim3(NBS * NH), 256, 0, stream>>>(hsb, Wb2, bq, bk, bv, amask, bits, qg, out);
}

// Round 17
// 218.299 us; speedup vs baseline: 2.5320x; 1.0095x over previous
//
#include <hip/hip_runtime.h>
#include <hip/hip_bf16.h>

// Problem constants
#define NBS   128
#define NF    182      // 20 text + 150 ocr/obj + 12 decode
#define NP    192      // padded N for MFMA tiling
#define DMODEL 768
#define NH    12
#define HDIM  64
#define SEQT  20
#define ROCR  150

typedef __attribute__((ext_vector_type(4))) float  f32x4;
typedef __attribute__((ext_vector_type(8))) short  s16x8;
typedef __attribute__((ext_vector_type(4))) unsigned int u32x4;
using bf16 = __hip_bfloat16;

#define SB()    __builtin_amdgcn_sched_barrier(0)
#define BAR()   __builtin_amdgcn_s_barrier()

// global->LDS direct copy, 16B per lane. LDS dest linear in lane (base+lane*16).
__device__ __forceinline__ void gload_lds16(const void* g, void* l) {
    auto gp = (const __attribute__((address_space(1))) unsigned int*)((unsigned long long)g);
    auto lp = (__attribute__((address_space(3))) unsigned int*)(unsigned int)((unsigned long long)l);
    __builtin_amdgcn_global_load_lds(gp, lp, 16, 0, 0);
}

// ---------------------------------------------------------------------------
// Kernel 0: PREP (convert + pack_adj merged).
// Blocks [0, 9600): fp32->bf16: hs -> hsb; Wq|Wk|Wv -> Wb2 per-head layout
//   (Wb2 row R = h*192 + which*64 + r0 holds W_which[h*64+r0][:]).
// Blocks [9600, 28800): pack spatial adjacency -> bitmask (b,12,150,3).
// ---------------------------------------------------------------------------
#define CVT_BLOCKS 9600
__global__ __launch_bounds__(256) void prep(
    const float* __restrict__ hs,
    const float* __restrict__ Wq, const float* __restrict__ Wk, const float* __restrict__ Wv,
    const float* __restrict__ adj,
    bf16* __restrict__ hsb, bf16* __restrict__ Wb2,
    unsigned long long* __restrict__ bits)
{
    __shared__ float tile[ROCR * NH];       // used by pack branch only
    if (blockIdx.x < CVT_BLOCKS) {
        const size_t HT = (size_t)NBS * NF * DMODEL / 8;        // 2,236,416
        const size_t WT = 3ull * DMODEL * DMODEL / 8;           // 221,184
        size_t i = (size_t)blockIdx.x * 256 + threadIdx.x;
        if (i >= HT + WT) return;
        const float* src; bf16* dst;
        if (i < HT) {
            size_t e = i * 8; src = hs + e; dst = hsb + e;
        } else {
            size_t e = (i - HT) * 8;
            int R = (int)(e / DMODEL), c = (int)(e % DMODEL);
            int h = R / 192, t2 = (R % 192) / 64, r0 = R % 64;
            src = (t2 == 0 ? Wq : t2 == 1 ? Wk : Wv) + (size_t)(h * 64 + r0) * DMODEL + c;
            dst = Wb2 + e;
        }
        float4 a = *reinterpret_cast<const float4*>(src);
        float4 b = *reinterpret_cast<const float4*>(src + 4);
        union { s16x8 v; bf16 h8[8]; } u;
        u.h8[0] = __float2bfloat16(a.x); u.h8[1] = __float2bfloat16(a.y);
        u.h8[2] = __float2bfloat16(a.z); u.h8[3] = __float2bfloat16(a.w);
        u.h8[4] = __float2bfloat16(b.x); u.h8[5] = __float2bfloat16(b.y);
        u.h8[6] = __float2bfloat16(b.z); u.h8[7] = __float2bfloat16(b.w);
        *reinterpret_cast<s16x8*>(dst) = u.v;
    } else {
        const int pb = blockIdx.x - CVT_BLOCKS;
        const int b = pb / ROCR, r = pb - b * ROCR;
        const int tid = threadIdx.x, lane = tid & 63, w = tid >> 6;
        const float* src = adj + ((size_t)b * ROCR + r) * (ROCR * NH);
        for (int i = tid; i < ROCR * NH; i += 256) tile[i] = src[i];
        __syncthreads();
        for (int c = w; c < NH * 3; c += 4) {
            int hh = c / 3, wd = c - hh * 3;
            int k = wd * 64 + lane;
            int j = k - SEQT;
            bool v = false;
            if (j >= 0 && j < ROCR) v = (tile[j * NH + hh] > 0.5f);
            unsigned long long m = __ballot(v);
            if (lane == 0) bits[(((size_t)b * NH + hh) * ROCR + r) * 3 + wd] = m;
        }
    }
}

// ---------------------------------------------------------------------------
// Kernel 2: FUSED per-(b,h) QKV-projection + attention.
// R16 body (verified) with the staging pipeline deepened 2 -> 3 buffers:
// 3 x 24KB staging (72KB LDS; 2 blocks x 72KB = 144KB <= 160K so residency
// unchanged). Steady state keeps 3 tiles (18 loads) in flight, vmcnt(12) —
// each tile gets ~2 iterations of latency budget instead of ~1 (R16 diagnosed
// stage-latency-bound: MFMA content ~11us, HBM 15%, occupancy register-capped
// at 2 waves/SIMD -> per-iter L2 latency was exposed).
// LDS map:
//   [0..24576)      staging buf0 -> K[192][64] swz after GEMM
//   [24576..49152)  staging buf1 -> Vt[64][192] swz after GEMM
//   [49152..73728)  staging buf2 (GEMM only)
// ---------------------------------------------------------------------------
#define KO2   0
#define VTO2  24576

__global__ __launch_bounds__(256, 2) void fused_qkv_attn(
    const bf16* __restrict__ hsb, const bf16* __restrict__ Wb2,
    const float* __restrict__ bq, const float* __restrict__ bk, const float* __restrict__ bv,
    const float* __restrict__ amask,
    const unsigned long long* __restrict__ bits,
    bf16* __restrict__ qg,
    float* __restrict__ out)
{
    __shared__ char L[73728];
    const int tid  = threadIdx.x;
    const int lane = tid & 63;
    const int wid  = tid >> 6;
    const int wr = wid >> 1, wc = wid & 1;      // 2x2 wave grid, 96x96 each
    const int lm = lane & 15, lg = lane >> 4;

    // m204 XCD chunking (1536 = 8*192): 12 head-blocks of one b on one XCD.
    const int flat = blockIdx.x;
    const int wgid = (flat & 7) * 192 + (flat >> 3);
    const int b = wgid / NH, h = wgid - b * NH;

    float* obase = out + (size_t)b * NF * DMODEL + h * HDIM;
    bf16*  qgb   = qg + (size_t)wgid * (176 * 64);

    // ---- aw: amask ballot words, per-wave registers (no LDS, no sync) ----
    unsigned long long aw0, aw1, aw2;
    {
        int k0 = lane, k1 = 64 + lane, k2 = 128 + lane;
        aw0 = __ballot(amask[b * NF + k0] == 0.0f);
        aw1 = __ballot(amask[b * NF + k1] == 0.0f);
        aw2 = __ballot((k2 < NF) && (amask[b * NF + k2] == 0.0f));
    }
    // decode output rows are exactly zero
    for (int i = tid; i < 12 * 64; i += 256)
        obase[(size_t)(170 + (i >> 6)) * DMODEL + (i & 63)] = 0.f;

    // ---- Phase G: GEMM (BK=32, 3-deep staging pipeline, vmcnt(12)) ----
    const char* gA = (const char*)(hsb + (size_t)b * NF * DMODEL);   // 192 rows (pad rows harmless)
    const char* gW = (const char*)(Wb2 + (size_t)h * 192 * DMODEL);

    f32x4 acc[6][6];
    #pragma unroll
    for (int i = 0; i < 6; ++i)
        #pragma unroll
        for (int j = 0; j < 6; ++j) acc[i][j] = (f32x4){0.f, 0.f, 0.f, 0.f};

    const int srow4 = tid >> 2, sch4 = tid & 3;

    auto ST = [&](int kt, int bsel) {
        char* dA = L + bsel * 24576;
        char* dW = dA + 12288;
        #pragma unroll
        for (int it = 0; it < 3; ++it) {
            int row = it * 64 + srow4;
            int lc = sch4 ^ ((row >> 1) & 3);
            size_t go = (size_t)row * 1536 + (size_t)kt * 64 + lc * 16;
            int o = row * 64 + sch4 * 16;
            gload_lds16(gA + go, dA + o);
            gload_lds16(gW + go, dW + o);
        }
    };
    auto CP = [&](int bsel) {
        const char* Ab = L + bsel * 24576;
        const char* Wp = Ab + 12288;
        s16x8 af[6], bf6[6];
        #pragma unroll
        for (int mi = 0; mi < 6; ++mi) {
            int r = 96 * wr + 16 * mi + lm;
            af[mi] = *reinterpret_cast<const s16x8*>(Ab + r * 64 + ((lg ^ ((r >> 1) & 3)) << 4));
        }
        #pragma unroll
        for (int ni = 0; ni < 6; ++ni) {
            int r = 96 * wc + 16 * ni + lm;
            bf6[ni] = *reinterpret_cast<const s16x8*>(Wp + r * 64 + ((lg ^ ((r >> 1) & 3)) << 4));
        }
        __builtin_amdgcn_s_setprio(1);
        #pragma unroll
        for (int mi = 0; mi < 6; ++mi)
            #pragma unroll
            for (int ni = 0; ni < 6; ++ni)
                acc[mi][ni] = __builtin_amdgcn_mfma_f32_16x16x32_bf16(af[mi], bf6[ni], acc[mi][ni], 0, 0, 0);
        __builtin_amdgcn_s_setprio(0);
    };

    ST(0, 0);
    ST(1, 1);
    ST(2, 2);
    for (int t = 0; t < 24; ++t) {
        if (t <= 21)      { asm volatile("s_waitcnt vmcnt(12)" ::: "memory"); }
        else if (t == 22) { asm volatile("s_waitcnt vmcnt(6)"  ::: "memory"); }
        else              { asm volatile("s_waitcnt vmcnt(0)"  ::: "memory"); }
        SB(); BAR(); SB();
        CP(t % 3);
        SB(); BAR();
        if (t + 3 < 24) ST(t + 3, t % 3);
    }
    BAR();   // all CP reads done before epilogue overwrites staging region

    // ---- epilogue (SINGLE PASS): acc+bias -> Q global / K LDS / Vt LDS ----
    float bias6[6];
    #pragma unroll
    for (int ni = 0; ni < 6; ++ni) {
        int c = 96 * wc + 16 * ni + lm;
        int whichc = c >> 6, cc = c & 63;
        const float* bp = (whichc == 0) ? bq : (whichc == 1) ? bk : bv;
        bias6[ni] = bp[h * 64 + cc];
    }
    #pragma unroll
    for (int mi = 0; mi < 6; ++mi) {
        #pragma unroll
        for (int ni = 0; ni < 6; ++ni) {
            int c = 96 * wc + 16 * ni + lm;
            #pragma unroll
            for (int j = 0; j < 4; ++j) {
                int row = 96 * wr + 16 * mi + 4 * lg + j;
                bf16 hv = __float2bfloat16(acc[mi][ni][j] + bias6[ni]);
                unsigned short us = *reinterpret_cast<unsigned short*>(&hv);
                if (c < 64) {
                    if (row < 176) qgb[row * 64 + c] = hv;
                } else if (c < 128) {
                    int cc = c - 64;
                    *reinterpret_cast<unsigned short*>(L + KO2 + row * 128 + ((2 * cc) ^ ((row & 7) << 4))) = us;
                } else if (row < NF) {
                    int d = c - 128;
                    *reinterpret_cast<unsigned short*>(L + VTO2 + d * 384 + ((2 * row) ^ ((d & 7) << 4))) = us;
                }
            }
        }
    }
    // zero Vt pad keys 182..191 (NaN containment)
    for (int i = tid; i < 64 * 10; i += 256) {
        int d = i / 10, k2 = NF + (i - d * 10);
        *reinterpret_cast<unsigned short*>(L + VTO2 + d * 384 + ((2 * k2) ^ ((d & 7) << 4))) = 0;
    }
    __syncthreads();    // drains vmcnt+lgkm: Q global writes + K/Vt LDS visible

    // ---- Q-preload from global (L2-hot, block-private region) ----
    s16x8 qf[3][2];
    #pragma unroll
    for (int bi = 0; bi < 3; ++bi) {
        int band = wid + 4 * bi;
        int qrow = ((band < 11) ? band * 16 : 0) + lm;      // safe dummy for band>=11
        const bf16* qb = qgb + qrow * 64;
        qf[bi][0] = *reinterpret_cast<const s16x8*>(qb + lg * 8);
        qf[bi][1] = *reinterpret_cast<const s16x8*>(qb + 32 + lg * 8);
    }

    // ---- Phase A: attention, P fully in-register (verified body) ----
    const unsigned long long* bbase = bits + ((size_t)b * NH + h) * ROCR * 3;
    const unsigned long long DEC = 0xFFFull << 42;          // keys 170..181

    #pragma unroll
    for (int bi = 0; bi < 3; ++bi) {
        const int band = wid + 4 * bi;
        if (band >= 11) continue;
        const int q0 = band * 16;

        // masks for this lane's q-row, straight from global bits (L2-hot)
        const int qrow = q0 + lm;
        unsigned long long mw0, mw1, mw2;
        if (qrow < SEQT) {
            mw0 = 0; mw1 = 0; mw2 = DEC & aw2;
        } else {
            const unsigned long long* bp = bbase + (size_t)(qrow - SEQT) * 3;
            mw0 = bp[0] & aw0;
            mw1 = bp[1] & aw1;
            mw2 = (bp[2] | DEC) & aw2;
        }

        // swapped QK^T: sacc[t][j] = S[key=16t+4lg+j][qrow=q0+lm]
        f32x4 sacc[12];
        #pragma unroll
        for (int t = 0; t < 12; ++t) sacc[t] = (f32x4){0.f, 0.f, 0.f, 0.f};
        #pragma unroll
        for (int t = 0; t < 12; ++t) {
            int key = t * 16 + lm;
            const char* kb = L + KO2 + key * 128;
            int sw = (key & 7) << 4;
            s16x8 kf0 = *reinterpret_cast<const s16x8*>(kb + ((lg * 16) ^ sw));
            s16x8 kf1 = *reinterpret_cast<const s16x8*>(kb + ((64 + lg * 16) ^ sw));
            sacc[t] = __builtin_amdgcn_mfma_f32_16x16x32_bf16(kf0, qf[bi][0], sacc[t], 0, 0, 0);
            sacc[t] = __builtin_amdgcn_mfma_f32_16x16x32_bf16(kf1, qf[bi][1], sacc[t], 0, 0, 0);
        }

        // mask + per-lane softmax (this lane owns one q-row)
        float mx = -3.0e38f;
        #pragma unroll
        for (int t = 0; t < 12; ++t) {
            unsigned long long w = (t < 4) ? mw0 : (t < 8) ? mw1 : mw2;
            #pragma unroll
            for (int j = 0; j < 4; ++j) {
                int sh = ((t & 3) << 4) + 4 * lg + j;
                float s = sacc[t][j] * 0.125f;
                s = ((w >> sh) & 1ull) ? s : -3.0e38f;
                sacc[t][j] = s;
                mx = fmaxf(mx, s);
            }
        }
        mx = fmaxf(mx, __shfl_xor(mx, 16));
        mx = fmaxf(mx, __shfl_xor(mx, 32));
        float sum = 0.f;
        #pragma unroll
        for (int t = 0; t < 12; ++t)
            #pragma unroll
            for (int j = 0; j < 4; ++j) {
                float e = (sacc[t][j] > -1.0e37f) ? __expf(sacc[t][j] - mx) : 0.f;
                sacc[t][j] = e;
                sum += e;
            }
        sum += __shfl_xor(sum, 16);
        sum += __shfl_xor(sum, 32);
        float scl = (mx > -1.0e37f) ? 1.0f / sum : 0.f;

        // pack P rows to bf16 dword pairs per tile
        unsigned int p0[12], p1[12];
        #pragma unroll
        for (int t = 0; t < 12; ++t) {
            bf16 b0 = __float2bfloat16(sacc[t][0] * scl);
            bf16 b1 = __float2bfloat16(sacc[t][1] * scl);
            bf16 b2 = __float2bfloat16(sacc[t][2] * scl);
            bf16 b3 = __float2bfloat16(sacc[t][3] * scl);
            p0[t] = (unsigned int)*reinterpret_cast<unsigned short*>(&b0)
                  | ((unsigned int)*reinterpret_cast<unsigned short*>(&b1) << 16);
            p1[t] = (unsigned int)*reinterpret_cast<unsigned short*>(&b2)
                  | ((unsigned int)*reinterpret_cast<unsigned short*>(&b3) << 16);
        }

        // PV: build A-frags by lane exchange; dest (lg,ks) = keys 32ks+8lg+0..7
        f32x4 oacc[4];
        #pragma unroll
        for (int t = 0; t < 4; ++t) oacc[t] = (f32x4){0.f, 0.f, 0.f, 0.f};
        const bool hi = (lg & 1);
        #pragma unroll
        for (int ks = 0; ks < 6; ++ks) {
            unsigned int A0 = p0[2 * ks],     A1 = p1[2 * ks];
            unsigned int B0 = p0[2 * ks + 1], B1 = p1[2 * ks + 1];
            unsigned int u0 = __shfl_xor(A0, 16), u1 = __shfl_xor(A1, 16);
            unsigned int v0 = __shfl_xor(B0, 16), v1 = __shfl_xor(B1, 16);
            unsigned int hA0 = hi ? u0 : A0, hA1 = hi ? u1 : A1;
            unsigned int hA2 = hi ? A0 : u0, hA3 = hi ? A1 : u1;
            unsigned int hB0 = hi ? v0 : B0, hB1 = hi ? v1 : B1;
            unsigned int hB2 = hi ? B0 : v0, hB3 = hi ? B1 : v1;
            unsigned int xA0 = __shfl_xor(hA0, 32), xA1 = __shfl_xor(hA1, 32);
            unsigned int xA2 = __shfl_xor(hA2, 32), xA3 = __shfl_xor(hA3, 32);
            unsigned int xB0 = __shfl_xor(hB0, 32), xB1 = __shfl_xor(hB1, 32);
            unsigned int xB2 = __shfl_xor(hB2, 32), xB3 = __shfl_xor(hB3, 32);
            u32x4 f;
            if (lg == 0)      f = (u32x4){hA0, hA1, hA2, hA3};
            else if (lg == 1) f = (u32x4){xA0, xA1, xA2, xA3};
            else if (lg == 2) f = (u32x4){xB0, xB1, xB2, xB3};
            else              f = (u32x4){hB0, hB1, hB2, hB3};
            s16x8 pa;
            __builtin_memcpy(&pa, &f, 16);
            #pragma unroll
            for (int t2 = 0; t2 < 4; ++t2) {
                int d = t2 * 16 + lm;
                s16x8 vf = *reinterpret_cast<const s16x8*>(L + VTO2 + d * 384 + ((ks * 64 + lg * 16) ^ ((d & 7) << 4)));
                oacc[t2] = __builtin_amdgcn_mfma_f32_16x16x32_bf16(pa, vf, oacc[t2], 0, 0, 0);
            }
        }
        #pragma unroll
        for (int j = 0; j < 4; ++j) {
            int row = q0 + lg * 4 + j;
            if (row < 170) {
                #pragma unroll
                for (int t2 = 0; t2 < 4; ++t2)
                    obase[(size_t)row * DMODEL + t2 * 16 + lm] = oacc[t2][j];
            }
        }
    }
}

// ---------------------------------------------------------------------------
extern "C" void kernel_launch(void* const* d_in, const int* in_sizes, int n_in,
                              void* d_out, int out_size, void* d_ws, size_t ws_size,
                              hipStream_t stream)
{
    const float* hs    = (const float*)d_in[0];
    const float* amask = (const float*)d_in[1];
    const float* adj   = (const float*)d_in[2];
    const float* Wq    = (const float*)d_in[3];
    const float* bq    = (const float*)d_in[4];
    const float* Wk    = (const float*)d_in[5];
    const float* bk    = (const float*)d_in[6];
    const float* Wv    = (const float*)d_in[7];
    const float* bv    = (const float*)d_in[8];
    float* out = (float*)d_out;

    // workspace: Wb2 (3.54MB) | bits (5.53MB) | hsb (35.8MB) | qg (34.6MB)
    // (qg after hsb also provides the pad-row read slack for b=127)
    char* ws = (char*)d_ws;
    bf16* Wb2 = (bf16*)ws;                                       // 2304*768*2 = 3,538,944
    unsigned long long* bits = (unsigned long long*)(ws + 3538944);
    bf16* hsb = (bf16*)(ws + 3538944 + 5529600);                 // 23296*768*2 = 35,782,656
    bf16* qg  = (bf16*)(ws + 3538944 + 5529600 + 35782656);      // 1536*176*64*2 = 34,603,008

    prep<<<dim3(CVT_BLOCKS + ROCR * NBS), 256, 0, stream>>>(hs, Wq, Wk, Wv, adj, hsb, Wb2, bits);
    fused_qkv_attn<<<dim3(NBS * NH), 256, 0, stream>>>(hsb, Wb2, bq, bk, bv, amask, bits, qg, out);
}

// Round 18
// 202.260 us; speedup vs baseline: 2.7328x; 1.0793x over previous
//
#include <hip/hip_runtime.h>
#include <hip/hip_bf16.h>

// Problem constants
#define NBS   128
#define NF    182      // 20 text + 150 ocr/obj + 12 decode
#define NP    192      // padded N for MFMA tiling
#define DMODEL 768
#define NH    12
#define HDIM  64
#define SEQT  20
#define ROCR  150

typedef __attribute__((ext_vector_type(4))) float  f32x4;
typedef __attribute__((ext_vector_type(8))) short  s16x8;
typedef __attribute__((ext_vector_type(4))) unsigned int u32x4;
using bf16 = __hip_bfloat16;

#define SB()    __builtin_amdgcn_sched_barrier(0)
#define BAR()   __builtin_amdgcn_s_barrier()

// global->LDS direct copy, 16B per lane. LDS dest linear in lane (base+lane*16).
__device__ __forceinline__ void gload_lds16(const void* g, void* l) {
    auto gp = (const __attribute__((address_space(1))) unsigned int*)((unsigned long long)g);
    auto lp = (__attribute__((address_space(3))) unsigned int*)(unsigned int)((unsigned long long)l);
    __builtin_amdgcn_global_load_lds(gp, lp, 16, 0, 0);
}

// ---------------------------------------------------------------------------
// Kernel 0: PREP (convert + pack_adj merged).
// Blocks [0, 9600): fp32->bf16: hs -> hsb; Wq|Wk|Wv -> Wb2 per-head layout
//   (Wb2 row R = h*192 + which*64 + r0 holds W_which[h*64+r0][:]).
// Blocks [9600, 28800): pack spatial adjacency -> bitmask (b,12,150,3).
// ---------------------------------------------------------------------------
#define CVT_BLOCKS 9600
__global__ __launch_bounds__(256) void prep(
    const float* __restrict__ hs,
    const float* __restrict__ Wq, const float* __restrict__ Wk, const float* __restrict__ Wv,
    const float* __restrict__ adj,
    bf16* __restrict__ hsb, bf16* __restrict__ Wb2,
    unsigned long long* __restrict__ bits)
{
    __shared__ float tile[ROCR * NH];       // used by pack branch only
    if (blockIdx.x < CVT_BLOCKS) {
        const size_t HT = (size_t)NBS * NF * DMODEL / 8;        // 2,236,416
        const size_t WT = 3ull * DMODEL * DMODEL / 8;           // 221,184
        size_t i = (size_t)blockIdx.x * 256 + threadIdx.x;
        if (i >= HT + WT) return;
        const float* src; bf16* dst;
        if (i < HT) {
            size_t e = i * 8; src = hs + e; dst = hsb + e;
        } else {
            size_t e = (i - HT) * 8;
            int R = (int)(e / DMODEL), c = (int)(e % DMODEL);
            int h = R / 192, t2 = (R % 192) / 64, r0 = R % 64;
            src = (t2 == 0 ? Wq : t2 == 1 ? Wk : Wv) + (size_t)(h * 64 + r0) * DMODEL + c;
            dst = Wb2 + e;
        }
        float4 a = *reinterpret_cast<const float4*>(src);
        float4 b = *reinterpret_cast<const float4*>(src + 4);
        union { s16x8 v; bf16 h8[8]; } u;
        u.h8[0] = __float2bfloat16(a.x); u.h8[1] = __float2bfloat16(a.y);
        u.h8[2] = __float2bfloat16(a.z); u.h8[3] = __float2bfloat16(a.w);
        u.h8[4] = __float2bfloat16(b.x); u.h8[5] = __float2bfloat16(b.y);
        u.h8[6] = __float2bfloat16(b.z); u.h8[7] = __float2bfloat16(b.w);
        *reinterpret_cast<s16x8*>(dst) = u.v;
    } else {
        const int pb = blockIdx.x - CVT_BLOCKS;
        const int b = pb / ROCR, r = pb - b * ROCR;
        const int tid = threadIdx.x, lane = tid & 63, w = tid >> 6;
        const float* src = adj + ((size_t)b * ROCR + r) * (ROCR * NH);
        for (int i = tid; i < ROCR * NH; i += 256) tile[i] = src[i];
        __syncthreads();
        for (int c = w; c < NH * 3; c += 4) {
            int hh = c / 3, wd = c - hh * 3;
            int k = wd * 64 + lane;
            int j = k - SEQT;
            bool v = false;
            if (j >= 0 && j < ROCR) v = (tile[j * NH + hh] > 0.5f);
            unsigned long long m = __ballot(v);
            if (lane == 0) bits[(((size_t)b * NH + hh) * ROCR + r) * 3 + wd] = m;
        }
    }
}

// ---------------------------------------------------------------------------
// Kernel 2: FUSED per-(b,h) QKV-projection + attention.
// R17 body with: (1) Q back in LDS — buf2 of the 3-deep staging pipeline
// becomes the Q region after the last CP (R9/R13-verified layout+preload);
// qg round-trip (~70MB HBM) deleted. (2) 0.125 score scale folded into Q at
// epilogue (exact pow2 in bf16) — removes 48 v_mul per band. (3) Vt epilogue
// writes packed as b64 (4 keys) where fully in-range; pad keys 182..191
// written only by the zero loop (disjoint -> race-free).
// LDS map:
//   [0..24576)      staging buf0 -> K[192][64] swz after GEMM
//   [24576..49152)  staging buf1 -> Vt[64][192] swz after GEMM
//   [49152..73728)  staging buf2 -> Q[192][64] swz after GEMM
// ---------------------------------------------------------------------------
#define KO2   0
#define VTO2  24576
#define QO3   49152

__global__ __launch_bounds__(256, 2) void fused_qkv_attn(
    const bf16* __restrict__ hsb, const bf16* __restrict__ Wb2,
    const float* __restrict__ bq, const float* __restrict__ bk, const float* __restrict__ bv,
    const float* __restrict__ amask,
    const unsigned long long* __restrict__ bits,
    float* __restrict__ out)
{
    __shared__ char L[73728];
    const int tid  = threadIdx.x;
    const int lane = tid & 63;
    const int wid  = tid >> 6;
    const int wr = wid >> 1, wc = wid & 1;      // 2x2 wave grid, 96x96 each
    const int lm = lane & 15, lg = lane >> 4;

    // m204 XCD chunking (1536 = 8*192): 12 head-blocks of one b on one XCD.
    const int flat = blockIdx.x;
    const int wgid = (flat & 7) * 192 + (flat >> 3);
    const int b = wgid / NH, h = wgid - b * NH;

    float* obase = out + (size_t)b * NF * DMODEL + h * HDIM;

    // ---- aw: amask ballot words, per-wave registers (no LDS, no sync) ----
    unsigned long long aw0, aw1, aw2;
    {
        int k0 = lane, k1 = 64 + lane, k2 = 128 + lane;
        aw0 = __ballot(amask[b * NF + k0] == 0.0f);
        aw1 = __ballot(amask[b * NF + k1] == 0.0f);
        aw2 = __ballot((k2 < NF) && (amask[b * NF + k2] == 0.0f));
    }
    // decode output rows are exactly zero
    for (int i = tid; i < 12 * 64; i += 256)
        obase[(size_t)(170 + (i >> 6)) * DMODEL + (i & 63)] = 0.f;

    // ---- Phase G: GEMM (BK=32, 3-deep staging pipeline, vmcnt(12)) ----
    const char* gA = (const char*)(hsb + (size_t)b * NF * DMODEL);   // 192 rows (pad rows in slack)
    const char* gW = (const char*)(Wb2 + (size_t)h * 192 * DMODEL);

    f32x4 acc[6][6];
    #pragma unroll
    for (int i = 0; i < 6; ++i)
        #pragma unroll
        for (int j = 0; j < 6; ++j) acc[i][j] = (f32x4){0.f, 0.f, 0.f, 0.f};

    const int srow4 = tid >> 2, sch4 = tid & 3;

    auto ST = [&](int kt, int bsel) {
        char* dA = L + bsel * 24576;
        char* dW = dA + 12288;
        #pragma unroll
        for (int it = 0; it < 3; ++it) {
            int row = it * 64 + srow4;
            int lc = sch4 ^ ((row >> 1) & 3);
            size_t go = (size_t)row * 1536 + (size_t)kt * 64 + lc * 16;
            int o = row * 64 + sch4 * 16;
            gload_lds16(gA + go, dA + o);
            gload_lds16(gW + go, dW + o);
        }
    };
    auto CP = [&](int bsel) {
        const char* Ab = L + bsel * 24576;
        const char* Wp = Ab + 12288;
        s16x8 af[6], bf6[6];
        #pragma unroll
        for (int mi = 0; mi < 6; ++mi) {
            int r = 96 * wr + 16 * mi + lm;
            af[mi] = *reinterpret_cast<const s16x8*>(Ab + r * 64 + ((lg ^ ((r >> 1) & 3)) << 4));
        }
        #pragma unroll
        for (int ni = 0; ni < 6; ++ni) {
            int r = 96 * wc + 16 * ni + lm;
            bf6[ni] = *reinterpret_cast<const s16x8*>(Wp + r * 64 + ((lg ^ ((r >> 1) & 3)) << 4));
        }
        __builtin_amdgcn_s_setprio(1);
        #pragma unroll
        for (int mi = 0; mi < 6; ++mi)
            #pragma unroll
            for (int ni = 0; ni < 6; ++ni)
                acc[mi][ni] = __builtin_amdgcn_mfma_f32_16x16x32_bf16(af[mi], bf6[ni], acc[mi][ni], 0, 0, 0);
        __builtin_amdgcn_s_setprio(0);
    };

    ST(0, 0);
    ST(1, 1);
    ST(2, 2);
    for (int t = 0; t < 24; ++t) {
        if (t <= 21)      { asm volatile("s_waitcnt vmcnt(12)" ::: "memory"); }
        else if (t == 22) { asm volatile("s_waitcnt vmcnt(6)"  ::: "memory"); }
        else              { asm volatile("s_waitcnt vmcnt(0)"  ::: "memory"); }
        SB(); BAR(); SB();
        CP(t % 3);
        SB(); BAR();
        if (t + 3 < 24) ST(t + 3, t % 3);
    }
    BAR();   // all CP reads done before epilogue overwrites staging region

    // ---- epilogue (SINGLE PASS): acc+bias -> Q/K/Vt LDS ----
    float bias6[6];
    #pragma unroll
    for (int ni = 0; ni < 6; ++ni) {
        int c = 96 * wc + 16 * ni + lm;
        int whichc = c >> 6, cc = c & 63;
        const float* bp = (whichc == 0) ? bq : (whichc == 1) ? bk : bv;
        bias6[ni] = bp[h * 64 + cc];
    }
    #pragma unroll
    for (int mi = 0; mi < 6; ++mi) {
        #pragma unroll
        for (int ni = 0; ni < 6; ++ni) {
            int c = 96 * wc + 16 * ni + lm;
            int row0 = 96 * wr + 16 * mi + 4 * lg;
            if (c < 64) {
                // Q, pre-scaled by 1/8 (exact pow2 in bf16)
                #pragma unroll
                for (int j = 0; j < 4; ++j) {
                    int row = row0 + j;
                    bf16 hv = __float2bfloat16((acc[mi][ni][j] + bias6[ni]) * 0.125f);
                    *reinterpret_cast<unsigned short*>(L + QO3 + row * 128 + ((2 * c) ^ ((row & 7) << 4))) =
                        *reinterpret_cast<unsigned short*>(&hv);
                }
            } else if (c < 128) {
                int cc = c - 64;
                #pragma unroll
                for (int j = 0; j < 4; ++j) {
                    int row = row0 + j;
                    bf16 hv = __float2bfloat16(acc[mi][ni][j] + bias6[ni]);
                    *reinterpret_cast<unsigned short*>(L + KO2 + row * 128 + ((2 * cc) ^ ((row & 7) << 4))) =
                        *reinterpret_cast<unsigned short*>(&hv);
                }
            } else {
                int d = c - 128;
                if (row0 + 3 < NF) {
                    union { unsigned long long u8; bf16 h[4]; } pk;
                    pk.h[0] = __float2bfloat16(acc[mi][ni][0] + bias6[ni]);
                    pk.h[1] = __float2bfloat16(acc[mi][ni][1] + bias6[ni]);
                    pk.h[2] = __float2bfloat16(acc[mi][ni][2] + bias6[ni]);
                    pk.h[3] = __float2bfloat16(acc[mi][ni][3] + bias6[ni]);
                    *reinterpret_cast<unsigned long long*>(L + VTO2 + d * 384 + ((2 * row0) ^ ((d & 7) << 4))) = pk.u8;
                } else {
                    #pragma unroll
                    for (int j = 0; j < 4; ++j) {
                        int row = row0 + j;
                        if (row < NF) {
                            bf16 hv = __float2bfloat16(acc[mi][ni][j] + bias6[ni]);
                            *reinterpret_cast<unsigned short*>(L + VTO2 + d * 384 + ((2 * row) ^ ((d & 7) << 4))) =
                                *reinterpret_cast<unsigned short*>(&hv);
                        }
                    }
                }
            }
        }
    }
    // zero Vt pad keys 182..191 (only writer of these addresses -> race-free)
    for (int i = tid; i < 64 * 10; i += 256) {
        int d = i / 10, k2 = NF + (i - d * 10);
        *reinterpret_cast<unsigned short*>(L + VTO2 + d * 384 + ((2 * k2) ^ ((d & 7) << 4))) = 0;
    }
    __syncthreads();

    // ---- Q-preload from LDS (R9-verified addressing) ----
    s16x8 qf[3][2];
    #pragma unroll
    for (int bi = 0; bi < 3; ++bi) {
        int band = wid + 4 * bi;
        int qrow = ((band < 11) ? band * 16 : 0) + lm;      // safe dummy for band>=11
        const char* qb = L + QO3 + qrow * 128;
        int sq = (qrow & 7) << 4;
        qf[bi][0] = *reinterpret_cast<const s16x8*>(qb + ((lg * 16) ^ sq));
        qf[bi][1] = *reinterpret_cast<const s16x8*>(qb + ((64 + lg * 16) ^ sq));
    }

    // ---- Phase A: attention, P fully in-register (verified body) ----
    const unsigned long long* bbase = bits + ((size_t)b * NH + h) * ROCR * 3;
    const unsigned long long DEC = 0xFFFull << 42;          // keys 170..181

    #pragma unroll
    for (int bi = 0; bi < 3; ++bi) {
        const int band = wid + 4 * bi;
        if (band >= 11) continue;
        const int q0 = band * 16;

        // masks for this lane's q-row, straight from global bits (L2-hot)
        const int qrow = q0 + lm;
        unsigned long long mw0, mw1, mw2;
        if (qrow < SEQT) {
            mw0 = 0; mw1 = 0; mw2 = DEC & aw2;
        } else {
            const unsigned long long* bp = bbase + (size_t)(qrow - SEQT) * 3;
            mw0 = bp[0] & aw0;
            mw1 = bp[1] & aw1;
            mw2 = (bp[2] | DEC) & aw2;
        }

        // swapped QK^T: sacc[t][j] = S[key=16t+4lg+j][qrow=q0+lm] (pre-scaled)
        f32x4 sacc[12];
        #pragma unroll
        for (int t = 0; t < 12; ++t) sacc[t] = (f32x4){0.f, 0.f, 0.f, 0.f};
        #pragma unroll
        for (int t = 0; t < 12; ++t) {
            int key = t * 16 + lm;
            const char* kb = L + KO2 + key * 128;
            int sw = (key & 7) << 4;
            s16x8 kf0 = *reinterpret_cast<const s16x8*>(kb + ((lg * 16) ^ sw));
            s16x8 kf1 = *reinterpret_cast<const s16x8*>(kb + ((64 + lg * 16) ^ sw));
            sacc[t] = __builtin_amdgcn_mfma_f32_16x16x32_bf16(kf0, qf[bi][0], sacc[t], 0, 0, 0);
            sacc[t] = __builtin_amdgcn_mfma_f32_16x16x32_bf16(kf1, qf[bi][1], sacc[t], 0, 0, 0);
        }

        // mask + per-lane softmax (this lane owns one q-row)
        float mx = -3.0e38f;
        #pragma unroll
        for (int t = 0; t < 12; ++t) {
            unsigned long long w = (t < 4) ? mw0 : (t < 8) ? mw1 : mw2;
            #pragma unroll
            for (int j = 0; j < 4; ++j) {
                int sh = ((t & 3) << 4) + 4 * lg + j;
                float s = sacc[t][j];
                s = ((w >> sh) & 1ull) ? s : -3.0e38f;
                sacc[t][j] = s;
                mx = fmaxf(mx, s);
            }
        }
        mx = fmaxf(mx, __shfl_xor(mx, 16));
        mx = fmaxf(mx, __shfl_xor(mx, 32));
        float sum = 0.f;
        #pragma unroll
        for (int t = 0; t < 12; ++t)
            #pragma unroll
            for (int j = 0; j < 4; ++j) {
                float e = (sacc[t][j] > -1.0e37f) ? __expf(sacc[t][j] - mx) : 0.f;
                sacc[t][j] = e;
                sum += e;
            }
        sum += __shfl_xor(sum, 16);
        sum += __shfl_xor(sum, 32);
        float scl = (mx > -1.0e37f) ? 1.0f / sum : 0.f;

        // pack P rows to bf16 dword pairs per tile
        unsigned int p0[12], p1[12];
        #pragma unroll
        for (int t = 0; t < 12; ++t) {
            bf16 b0 = __float2bfloat16(sacc[t][0] * scl);
            bf16 b1 = __float2bfloat16(sacc[t][1] * scl);
            bf16 b2 = __float2bfloat16(sacc[t][2] * scl);
            bf16 b3 = __float2bfloat16(sacc[t][3] * scl);
            p0[t] = (unsigned int)*reinterpret_cast<unsigned short*>(&b0)
                  | ((unsigned int)*reinterpret_cast<unsigned short*>(&b1) << 16);
            p1[t] = (unsigned int)*reinterpret_cast<unsigned short*>(&b2)
                  | ((unsigned int)*reinterpret_cast<unsigned short*>(&b3) << 16);
        }

        // PV: build A-frags by lane exchange; dest (lg,ks) = keys 32ks+8lg+0..7
        f32x4 oacc[4];
        #pragma unroll
        for (int t = 0; t < 4; ++t) oacc[t] = (f32x4){0.f, 0.f, 0.f, 0.f};
        const bool hi = (lg & 1);
        #pragma unroll
        for (int ks = 0; ks < 6; ++ks) {
            unsigned int A0 = p0[2 * ks],     A1 = p1[2 * ks];
            unsigned int B0 = p0[2 * ks + 1], B1 = p1[2 * ks + 1];
            unsigned int u0 = __shfl_xor(A0, 16), u1 = __shfl_xor(A1, 16);
            unsigned int v0 = __shfl_xor(B0, 16), v1 = __shfl_xor(B1, 16);
            unsigned int hA0 = hi ? u0 : A0, hA1 = hi ? u1 : A1;
            unsigned int hA2 = hi ? A0 : u0, hA3 = hi ? A1 : u1;
            unsigned int hB0 = hi ? v0 : B0, hB1 = hi ? v1 : B1;
            unsigned int hB2 = hi ? B0 : v0, hB3 = hi ? B1 : v1;
            unsigned int xA0 = __shfl_xor(hA0, 32), xA1 = __shfl_xor(hA1, 32);
            unsigned int xA2 = __shfl_xor(hA2, 32), xA3 = __shfl_xor(hA3, 32);
            unsigned int xB0 = __shfl_xor(hB0, 32), xB1 = __shfl_xor(hB1, 32);
            unsigned int xB2 = __shfl_xor(hB2, 32), xB3 = __shfl_xor(hB3, 32);
            u32x4 f;
            if (lg == 0)      f = (u32x4){hA0, hA1, hA2, hA3};
            else if (lg == 1) f = (u32x4){xA0, xA1, xA2, xA3};
            else if (lg == 2) f = (u32x4){xB0, xB1, xB2, xB3};
            else              f = (u32x4){hB0, hB1, hB2, hB3};
            s16x8 pa;
            __builtin_memcpy(&pa, &f, 16);
            #pragma unroll
            for (int t2 = 0; t2 < 4; ++t2) {
                int d = t2 * 16 + lm;
                s16x8 vf = *reinterpret_cast<const s16x8*>(L + VTO2 + d * 384 + ((ks * 64 + lg * 16) ^ ((d & 7) << 4)));
                oacc[t2] = __builtin_amdgcn_mfma_f32_16x16x32_bf16(pa, vf, oacc[t2], 0, 0, 0);
            }
        }
        #pragma unroll
        for (int j = 0; j < 4; ++j) {
            int row = q0 + lg * 4 + j;
            if (row < 170) {
                #pragma unroll
                for (int t2 = 0; t2 < 4; ++t2)
                    obase[(size_t)row * DMODEL + t2 * 16 + lm] = oacc[t2][j];
            }
        }
    }
}

// ---------------------------------------------------------------------------
extern "C" void kernel_launch(void* const* d_in, const int* in_sizes, int n_in,
                              void* d_out, int out_size, void* d_ws, size_t ws_size,
                              hipStream_t stream)
{
    const float* hs    = (const float*)d_in[0];
    const float* amask = (const float*)d_in[1];
    const float* adj   = (const float*)d_in[2];
    const float* Wq    = (const float*)d_in[3];
    const float* bq    = (const float*)d_in[4];
    const float* Wk    = (const float*)d_in[5];
    const float* bk    = (const float*)d_in[6];
    const float* Wv    = (const float*)d_in[7];
    const float* bv    = (const float*)d_in[8];
    float* out = (float*)d_out;

    // workspace: Wb2 (3.54MB) | bits (5.53MB) | hsb (35.8MB + 16KB pad-row slack)
    char* ws = (char*)d_ws;
    bf16* Wb2 = (bf16*)ws;                                       // 2304*768*2 = 3,538,944
    unsigned long long* bits = (unsigned long long*)(ws + 3538944);
    bf16* hsb = (bf16*)(ws + 3538944 + 5529600);                 // 23296*768*2 = 35,782,656 (+slack)

    prep<<<dim3(CVT_BLOCKS + ROCR * NBS), 256, 0, stream>>>(hs, Wq, Wk, Wv, adj, hsb, Wb2, bits);
    fused_qkv_attn<<<dim3(NBS * NH), 256, 0, stream>>>(hsb, Wb2, bq, bk, bv, amask, bits, out);
}